// Round 8
// baseline (424.199 us; speedup 1.0000x reference)
//
#include <hip/hip_runtime.h>
#include <hip/hip_bf16.h>
#include <stdint.h>
#include <stddef.h>

typedef _Float16 f16;
typedef __attribute__((ext_vector_type(8))) _Float16 f16x8;
typedef __attribute__((ext_vector_type(4))) _Float16 f16x4;
typedef __attribute__((ext_vector_type(4))) float f32x4;
typedef __attribute__((ext_vector_type(16))) float f32x16;

#define MFMA_F16(a, b, c) __builtin_amdgcn_mfma_f32_16x16x32_f16(a, b, c, 0, 0, 0)
#define MFMA32_F16(a, b, c) __builtin_amdgcn_mfma_f32_32x32x16_f16(a, b, c, 0, 0, 0)

#define LOG2_10K_32 0.41524101186092025f   // log2(10000)/32

__device__ __forceinline__ uint32_t swz(uint32_t ci) {
    return (ci & ~7u) | ((ci ^ (ci >> 3)) & 7u);
}

__device__ __forceinline__ void async_ld16(void* lds, const void* g) {
    __builtin_amdgcn_global_load_lds(
        (const __attribute__((address_space(1))) void*)g,
        (__attribute__((address_space(3))) void*)lds, 16, 0, 0);
}

// ---------------------------------------------------------------- prep: both W transposes in one launch
__global__ __launch_bounds__(256) void k_prep_w(
        const float* __restrict__ Wqkv, const float* __restrict__ Wout,
        f16* __restrict__ WqkvT, f16* __restrict__ WoutT) {
    __shared__ float tile[32][33];
    int x = threadIdx.x & 31, y = threadIdx.x >> 5;
    int bx = blockIdx.x;
    const float* S;
    f16* D;
    int rows, cols, bxe;
    if (bx < 96) { S = Wqkv; D = WqkvT; rows = 1024; cols = 3072; bxe = bx; }
    else         { S = Wout; D = WoutT; rows = 1024; cols = 1024; bxe = bx - 96; }
    int c0 = bxe * 32, r0 = blockIdx.y * 32;
#pragma unroll
    for (int i = 0; i < 32; i += 8)
        tile[y + i][x] = S[(size_t)(r0 + y + i) * cols + c0 + x];
    __syncthreads();
#pragma unroll
    for (int i = 0; i < 32; i += 8)
        D[(size_t)(c0 + y + i) * rows + r0 + x] = (f16)tile[x][y + i];
}

// ---------------------------------------------------------------- prep: RMSNorm + pmpad + RoPE trig table
// Table entries computed with the BYTE-IDENTICAL expression the old epilogue
// used ((float)n * exp2f(-LOG2_10K_32 * (float)j) -> sincosf) so the RoPE
// output stays bit-identical.
__global__ __launch_bounds__(256) void k_prep_x(
        const float* __restrict__ seq, const float* __restrict__ w, f16* __restrict__ X,
        const float* __restrict__ pm, f16* __restrict__ Kb, f16* __restrict__ Vt,
        float* __restrict__ RT) {
    __shared__ float red[4];
    const int b = blockIdx.x, t = threadIdx.x;
    if (b < 16384) {
        // ---- RMSNorm row b
        const float4* sp = (const float4*)(seq + (size_t)b * 1024);
        float4 v = sp[t];
        float ss = v.x * v.x + v.y * v.y + v.z * v.z + v.w * v.w;
#pragma unroll
        for (int off = 32; off >= 1; off >>= 1) ss += __shfl_xor(ss, off, 64);
        if ((t & 63) == 0) red[t >> 6] = ss;
        __syncthreads();
        float tot = red[0] + red[1] + red[2] + red[3];
        float rs = rsqrtf(tot * (1.0f / 1024.0f) + 1.1920929e-07f);
        const float4* wp = (const float4*)w;
        float4 wv = wp[t];
        f16x4 o;
        o[0] = (f16)(v.x * rs * wv.x);
        o[1] = (f16)(v.y * rs * wv.y);
        o[2] = (f16)(v.z * rs * wv.z);
        o[3] = (f16)(v.w * rs * wv.w);
        *(f16x4*)(X + (size_t)b * 1024 + t * 4) = o;
    } else if (b < 16896) {
        // ---- pmpad for wh = b - 16384
        int wh = b - 16384, h = wh & 15;
        const float* pk = pm + (size_t)h * 1024;
        f16* kb = Kb + (size_t)wh * 36864;
        int e0 = t * 4;
#pragma unroll
        for (int k = 0; k < 4; k++) kb[e0 + k] = (f16)pk[e0 + k];
#pragma unroll
        for (int k = 0; k < 12; k++) kb[33792 + t + k * 256] = (f16)0.f;
        const float* pv = pm + 16384 + (size_t)h * 1024;
        f16* vb = Vt + (size_t)wh * 36864;
        {
            int d = t & 63, s4 = (t >> 6) * 4;
#pragma unroll
            for (int k = 0; k < 4; k++)
                vb[(size_t)d * 576 + s4 + k] = (f16)pv[(s4 + k) * 64 + d];
        }
        {
            int d = t >> 2, rep = t & 3;
#pragma unroll
            for (int m = 0; m < 12; m++)
                vb[(size_t)d * 576 + 528 + rep * 12 + m] = (f16)0.f;
        }
    } else {
        // ---- RoPE table: 8192 pos x 32 j, float2 (cos,sin) each
        int bb = b - 16896;                    // 0..511
        int e0 = bb * 512 + t * 2;             // 2 entries/thread
#pragma unroll
        for (int u = 0; u < 2; u++) {
            int e = e0 + u;
            int n_ = e >> 5, j = e & 31;
            float ang = (float)n_ * exp2f(-LOG2_10K_32 * (float)j);
            float s, c;
            sincosf(ang, &s, &c);
            RT[2 * e] = c;
            RT[2 * e + 1] = s;
        }
    }
}

// ---------------------------------------------------------------- QKV GEMM (r5 structure + table-based RoPE)
__global__ __launch_bounds__(256) void k_gemm_qkv(
        const f16* __restrict__ A, const f16* __restrict__ BT,
        f16* __restrict__ Qb, f16* __restrict__ Kb, f16* __restrict__ Vt,
        const float* __restrict__ RT) {
    const int K = 1024;
    __shared__ f16 As[128 * 32];
    __shared__ f16 Bs[128 * 32];
    const int t = threadIdx.x;
    const int lane = t & 63, wave = t >> 6, l32 = lane & 31, half = lane >> 5;
    const int m0 = blockIdx.y * 128, n0 = blockIdx.x * 128;
    const int wm = (wave & 1) * 64, wn = (wave >> 1) * 64;
    f32x16 acc[2][2];
#pragma unroll
    for (int i = 0; i < 2; i++)
#pragma unroll
        for (int j = 0; j < 2; j++)
#pragma unroll
            for (int r = 0; r < 16; r++) acc[i][j][r] = 0.f;

    uint32_t aoff[2][2], boff[2][2];
#pragma unroll
    for (int bk = 0; bk < 2; bk++)
#pragma unroll
        for (int ks = 0; ks < 2; ks++) {
            aoff[bk][ks] = swz((uint32_t)(wm + bk * 32 + l32) * 4 + ks * 2 + half) * 16;
            boff[bk][ks] = swz((uint32_t)(wn + bk * 32 + l32) * 4 + ks * 2 + half) * 16;
        }
    uint32_t c0 = swz(t), c1 = swz(t + 256);
    const f16* Ag0 = A + (size_t)(m0 + (c0 >> 2)) * K + (c0 & 3) * 8;
    const f16* Ag1 = A + (size_t)(m0 + (c1 >> 2)) * K + (c1 & 3) * 8;
    const f16* Bg0 = BT + (size_t)(n0 + (c0 >> 2)) * K + (c0 & 3) * 8;
    const f16* Bg1 = BT + (size_t)(n0 + (c1 >> 2)) * K + (c1 & 3) * 8;
    char* AsB = (char*)As;
    char* BsB = (char*)Bs;

    for (int k0 = 0; k0 < K; k0 += 32) {
        __syncthreads();
        async_ld16(AsB + t * 16, Ag0 + k0);
        async_ld16(AsB + (t + 256) * 16, Ag1 + k0);
        async_ld16(BsB + t * 16, Bg0 + k0);
        async_ld16(BsB + (t + 256) * 16, Bg1 + k0);
        __builtin_amdgcn_s_waitcnt(0x0f70);  // vmcnt(0)
        __syncthreads();
        f16x8 a[2][2], b[2][2];
#pragma unroll
        for (int bk = 0; bk < 2; bk++)
#pragma unroll
            for (int ks = 0; ks < 2; ks++) {
                a[bk][ks] = *(const f16x8*)(AsB + aoff[bk][ks]);
                b[bk][ks] = *(const f16x8*)(BsB + boff[bk][ks]);
            }
#pragma unroll
        for (int mb = 0; mb < 2; mb++)
#pragma unroll
            for (int nb = 0; nb < 2; nb++) {
                acc[mb][nb] = MFMA32_F16(b[nb][0], a[mb][0], acc[mb][nb]);
                acc[mb][nb] = MFMA32_F16(b[nb][1], a[mb][1], acc[mb][nb]);
            }
    }

    // region uniform per block: 0=Q, 1=K, 2=V
    const int region = n0 >> 10;
#pragma unroll
    for (int mb = 0; mb < 2; mb++) {
        int row = m0 + wm + mb * 32 + l32;       // token 0..16383
        int b_ = row >> 13, n_ = row & 8191;
        int win = n_ >> 9, i_ = n_ & 511;
#pragma unroll
        for (int nb = 0; nb < 2; nb++) {
            int colb = n0 + wn + nb * 32 + half * 4;
            int cr = colb & 1023;                 // feature idx within region
            int h = cr >> 6;
            int d0 = cr & 63;                     // multiple of 4
            int wh = ((b_ * 16 + win) << 4) + h;
            if (region < 2) {
                f16* base = (region == 0)
                    ? (Qb + ((size_t)wh * 512 + i_) * 64)
                    : (Kb + ((size_t)wh * 576 + 16 + i_) * 64);
                const float4* tb = (const float4*)(RT + (size_t)n_ * 64);
#pragma unroll
                for (int q = 0; q < 4; q++) {
                    int d = d0 + q * 8;
                    float4 cs = tb[d >> 2];       // (cos j, sin j, cos j+1, sin j+1), j=d>>1
                    float x0 = (float)(f16)acc[mb][nb][q * 4 + 0];
                    float x1 = (float)(f16)acc[mb][nb][q * 4 + 1];
                    float x2 = (float)(f16)acc[mb][nb][q * 4 + 2];
                    float x3 = (float)(f16)acc[mb][nb][q * 4 + 3];
                    f16x4 ov;
                    ov[0] = (f16)(x0 * cs.x - x1 * cs.y);
                    ov[1] = (f16)(x1 * cs.x + x0 * cs.y);
                    ov[2] = (f16)(x2 * cs.z - x3 * cs.w);
                    ov[3] = (f16)(x3 * cs.z + x2 * cs.w);
                    *(f16x4*)(base + d) = ov;
                }
            } else {
                f16* vbase = Vt + (size_t)wh * 36864 + 16 + i_;
#pragma unroll
                for (int q = 0; q < 4; q++)
#pragma unroll
                    for (int r = 0; r < 4; r++)
                        vbase[(size_t)(d0 + q * 8 + r) * 576] = (f16)acc[mb][nb][q * 4 + r];
            }
        }
    }
}

// ---------------------------------------------------------------- out GEMM (r5 structure)
__global__ __launch_bounds__(256) void k_gemm_out(
        const f16* __restrict__ A, const f16* __restrict__ BT,
        float* __restrict__ C, int M, int N, int K) {
    __shared__ f16 As[128 * 32];
    __shared__ f16 Bs[128 * 32];
    const int t = threadIdx.x;
    const int lane = t & 63, wave = t >> 6, l32 = lane & 31, half = lane >> 5;
    const int m0 = blockIdx.y * 128, n0 = blockIdx.x * 128;
    const int wm = (wave & 1) * 64, wn = (wave >> 1) * 64;
    f32x16 acc[2][2];
#pragma unroll
    for (int i = 0; i < 2; i++)
#pragma unroll
        for (int j = 0; j < 2; j++)
#pragma unroll
            for (int r = 0; r < 16; r++) acc[i][j][r] = 0.f;

    uint32_t aoff[2][2], boff[2][2];
#pragma unroll
    for (int bk = 0; bk < 2; bk++)
#pragma unroll
        for (int ks = 0; ks < 2; ks++) {
            aoff[bk][ks] = swz((uint32_t)(wm + bk * 32 + l32) * 4 + ks * 2 + half) * 16;
            boff[bk][ks] = swz((uint32_t)(wn + bk * 32 + l32) * 4 + ks * 2 + half) * 16;
        }
    uint32_t c0 = swz(t), c1 = swz(t + 256);
    const f16* Ag0 = A + (size_t)(m0 + (c0 >> 2)) * K + (c0 & 3) * 8;
    const f16* Ag1 = A + (size_t)(m0 + (c1 >> 2)) * K + (c1 & 3) * 8;
    const f16* Bg0 = BT + (size_t)(n0 + (c0 >> 2)) * K + (c0 & 3) * 8;
    const f16* Bg1 = BT + (size_t)(n0 + (c1 >> 2)) * K + (c1 & 3) * 8;
    char* AsB = (char*)As;
    char* BsB = (char*)Bs;

    for (int k0 = 0; k0 < K; k0 += 32) {
        __syncthreads();
        async_ld16(AsB + t * 16, Ag0 + k0);
        async_ld16(AsB + (t + 256) * 16, Ag1 + k0);
        async_ld16(BsB + t * 16, Bg0 + k0);
        async_ld16(BsB + (t + 256) * 16, Bg1 + k0);
        __builtin_amdgcn_s_waitcnt(0x0f70);  // vmcnt(0)
        __syncthreads();
        f16x8 a[2][2], b[2][2];
#pragma unroll
        for (int bk = 0; bk < 2; bk++)
#pragma unroll
            for (int ks = 0; ks < 2; ks++) {
                a[bk][ks] = *(const f16x8*)(AsB + aoff[bk][ks]);
                b[bk][ks] = *(const f16x8*)(BsB + boff[bk][ks]);
            }
#pragma unroll
        for (int mb = 0; mb < 2; mb++)
#pragma unroll
            for (int nb = 0; nb < 2; nb++) {
                acc[mb][nb] = MFMA32_F16(b[nb][0], a[mb][0], acc[mb][nb]);
                acc[mb][nb] = MFMA32_F16(b[nb][1], a[mb][1], acc[mb][nb]);
            }
    }
#pragma unroll
    for (int mb = 0; mb < 2; mb++) {
        int row = m0 + wm + mb * 32 + l32;
#pragma unroll
        for (int nb = 0; nb < 2; nb++) {
            int colb = n0 + wn + nb * 32 + half * 4;
#pragma unroll
            for (int q = 0; q < 4; q++) {
                f32x4 ov;
#pragma unroll
                for (int r = 0; r < 4; r++) ov[r] = acc[mb][nb][q * 4 + r];
                *(f32x4*)(C + (size_t)row * N + colb + q * 8) = ov;
            }
        }
    }
}

// ---------------------------------------------------------------- attention (R11, unchanged)
__global__ __launch_bounds__(512) void k_attn(
        const f16* __restrict__ Q, const f16* __restrict__ Kb,
        const f16* __restrict__ Vt, f16* __restrict__ AO) {
    const int bid = blockIdx.x;
    const int wh = ((bid >> 5) << 3) | (bid & 7);   // bid = 32*(wh>>3) + 8*pair + (wh&7)
    const int pair = (bid >> 3) & 3;
    const int i0 = pair * 128;
    const int t = threadIdx.x, lane = t & 63, wave = t >> 6, quad = lane >> 4, l16 = lane & 15;
    __shared__ f16 Ks[64 * 64];
    __shared__ f16 Vs[64 * 64];
    __shared__ f16 Ps[8][16][80];

    const int ig = i0 + wave * 16 + l16;
    const f16* qptr = Q + ((size_t)wh * 512 + ig) * 64 + quad * 8;
    f16x8 qf0 = *(const f16x8*)(qptr);
    f16x8 qf1 = *(const f16x8*)(qptr + 32);

    const f32x4 zero = {0.f, 0.f, 0.f, 0.f};
    f32x4 o[4];
#pragma unroll
    for (int i = 0; i < 4; i++) o[i] = zero;
    float m_l = -1e30f, l_l = 0.f;

    uint32_t g = swz((uint32_t)t);                   // 512 granules, 1 load/thread
    const f16* kg0 = Kb + ((size_t)wh * 576 + (g >> 3)) * 64 + (g & 7) * 8;
    const f16* vg0 = Vt + ((size_t)wh * 64 + (g >> 3)) * 576 + (g & 7) * 8;
    char* KsB = (char*)Ks;
    char* VsB = (char*)Vs;

    uint32_t boff[4][2];
#pragma unroll
    for (int i = 0; i < 4; i++)
#pragma unroll
        for (int f = 0; f < 2; f++)
            boff[i][f] = swz((uint32_t)(i * 16 + l16) * 8 + f * 4 + quad) * 16;

    f16* psrow = &Ps[wave][l16][0];
    int njt = 2 * pair + 3;
    if (njt > 9) njt = 9;

    const int jcap = (ig + 16 < 527) ? (ig + 16) : 527;   // jg<=ig+16 && jg<528

    // prologue: load tile 0 into regs (pre-swizzled global addr, linear LDS dest)
    f16x8 kreg = *(const f16x8*)(kg0);
    f16x8 vreg = *(const f16x8*)(vg0);

    for (int jt = 0; jt < njt; jt++) {
        const int j0 = jt * 64;
        // B1: all waves done reading LDS of tile jt-1 (raw barrier: no vmcnt drain)
        __builtin_amdgcn_sched_barrier(0);
        __builtin_amdgcn_s_barrier();
        __builtin_amdgcn_sched_barrier(0);
        *(f16x8*)(KsB + t * 16) = kreg;
        *(f16x8*)(VsB + t * 16) = vreg;
        if (jt + 1 < njt) {
            kreg = *(const f16x8*)(kg0 + (size_t)(j0 + 64) * 64);
            vreg = *(const f16x8*)(vg0 + (j0 + 64));
        }
        // B2: this tile's LDS writes visible to all waves
        __builtin_amdgcn_s_waitcnt(0xc07f);  // lgkmcnt(0): own ds_writes done
        __builtin_amdgcn_sched_barrier(0);
        __builtin_amdgcn_s_barrier();
        __builtin_amdgcn_sched_barrier(0);

        f32x4 s[4];
#pragma unroll
        for (int jb = 0; jb < 4; jb++) {
            f16x8 kv0 = *(const f16x8*)(KsB + boff[jb][0]);
            f16x8 kv1 = *(const f16x8*)(KsB + boff[jb][1]);
            f32x4 z = zero;
            z = MFMA_F16(kv0, qf0, z);
            z = MFMA_F16(kv1, qf1, z);
            s[jb] = z;
        }

        // wave-uniform: tile fully unmasked for every lane of this wave?
        const bool fullt = (j0 + 63 <= i0 + wave * 16 + 16) && (j0 + 64 <= 528);
        float mx = -1e30f;
        if (fullt) {
#pragma unroll
            for (int jb = 0; jb < 4; jb++)
#pragma unroll
                for (int r = 0; r < 4; r++) {
                    float val = s[jb][r] * 0.125f;
                    s[jb][r] = val;
                    mx = fmaxf(mx, val);
                }
        } else {
#pragma unroll
            for (int jb = 0; jb < 4; jb++)
#pragma unroll
                for (int r = 0; r < 4; r++) {
                    int jg = j0 + jb * 16 + quad * 4 + r;
                    float val = (jg <= jcap) ? s[jb][r] * 0.125f : -1e30f;
                    s[jb][r] = val;
                    mx = fmaxf(mx, val);
                }
        }
        mx = fmaxf(mx, __shfl_xor(mx, 16, 64));
        mx = fmaxf(mx, __shfl_xor(mx, 32, 64));
        const bool skipresc = __all(mx <= m_l);        // -> mnew==m_l, alpha==1 exactly
        float mnew = fmaxf(m_l, mx);
        float alpha = 1.0f;
        if (!skipresc) alpha = __expf(m_l - mnew);
        m_l = mnew;
        float rsum = 0.f;
#pragma unroll
        for (int jb = 0; jb < 4; jb++) {
            f16x4 pw;
#pragma unroll
            for (int r = 0; r < 4; r++) {
                float p = __expf(s[jb][r] - mnew);
                rsum += p;
                pw[r] = (f16)p;
            }
            *(f16x4*)(psrow + jb * 16 + quad * 4) = pw;
        }
        rsum += __shfl_xor(rsum, 16, 64);
        rsum += __shfl_xor(rsum, 32, 64);
        if (skipresc) {
            l_l = l_l + rsum;                          // == l_l*1.0f + rsum bitwise
        } else {
            l_l = l_l * alpha + rsum;
#pragma unroll
            for (int nd = 0; nd < 4; nd++) o[nd] *= alpha;
        }

        // Ps is wave-local: wave-level DS completion suffices (no barrier)
        __builtin_amdgcn_s_waitcnt(0xc07f);  // lgkmcnt(0)
        __builtin_amdgcn_sched_barrier(0);

        f16x8 pb0 = *(const f16x8*)(psrow + quad * 8);
        f16x8 pb1 = *(const f16x8*)(psrow + 32 + quad * 8);
#pragma unroll
        for (int nd = 0; nd < 4; nd++) {
            f16x8 v0 = *(const f16x8*)(VsB + boff[nd][0]);
            f16x8 v1 = *(const f16x8*)(VsB + boff[nd][1]);
            o[nd] = MFMA_F16(v0, pb0, o[nd]);
            o[nd] = MFMA_F16(v1, pb1, o[nd]);
        }
    }

    const int bw = wh >> 4, h = wh & 15;
    float inv = 1.f / l_l;
    f16* dst = AO + ((size_t)bw * 512 + ig) * 1024 + h * 64 + quad * 4;
#pragma unroll
    for (int nd = 0; nd < 4; nd++) {
        f16x4 ov;
#pragma unroll
        for (int r = 0; r < 4; r++) ov[r] = (f16)(o[nd][r] * inv);
        *(f16x4*)(dst + nd * 16) = ov;
    }
}

// ---------------------------------------------------------------- launch
extern "C" void kernel_launch(void* const* d_in, const int* in_sizes, int n_in,
                              void* d_out, int out_size, void* d_ws, size_t ws_size,
                              hipStream_t stream) {
    const float* seq   = (const float*)d_in[0];
    const float* wnorm = (const float*)d_in[1];
    const float* Wqkv  = (const float*)d_in[2];
    const float* Wout  = (const float*)d_in[3];
    const float* pm    = (const float*)d_in[4];
    float* out = (float*)d_out;
    char* ws = (char*)d_ws;

    f16* WqkvT = (f16*)(ws + 0);            // 3072x1024  = 6 MB
    f16* WoutT = (f16*)(ws + 6291456);      // 1024x1024  = 2 MB
    f16* X     = (f16*)(ws + 8388608);      // 16384x1024 = 32 MB
    f16* Qb    = (f16*)(ws + 41943040);     // 512x512x64 = 32 MB
    f16* AO    = (f16*)(ws + 75497472);     // 16384x1024 = 32 MB
    f16* Kb    = (f16*)(ws + 109051904);    // 512x576x64 = 36 MB
    f16* Vt    = (f16*)(ws + 146800640);    // 512x64x576 = 36 MB  (end 176 MB)
    // RoPE table aliases the AO region: written by prep, read only by qkv,
    // then overwritten by attn (stream-serial -> safe, zero extra workspace)
    float* RT  = (float*)(ws + 75497472);   // 8192x32 float2 = 2 MB

    k_prep_w<<<dim3(128, 32), 256, 0, stream>>>(Wqkv, Wout, WqkvT, WoutT);
    k_prep_x<<<17408, 256, 0, stream>>>(seq, wnorm, X, pm, Kb, Vt, RT);
    k_gemm_qkv<<<dim3(24, 128), 256, 0, stream>>>(X, WqkvT, Qb, Kb, Vt, RT);
    k_attn<<<2048, 512, 0, stream>>>(Qb, Kb, Vt, AO);
    k_gemm_out<<<dim3(8, 128), 256, 0, stream>>>(AO, WoutT, out, 16384, 1024, 1024);
}

// Round 10
// 406.976 us; speedup vs baseline: 1.0423x; 1.0423x over previous
//
#include <hip/hip_runtime.h>
#include <hip/hip_bf16.h>
#include <stdint.h>
#include <stddef.h>

typedef _Float16 f16;
typedef __attribute__((ext_vector_type(8))) _Float16 f16x8;
typedef __attribute__((ext_vector_type(4))) _Float16 f16x4;
typedef __attribute__((ext_vector_type(4))) float f32x4;
typedef __attribute__((ext_vector_type(16))) float f32x16;

#define MFMA_F16(a, b, c) __builtin_amdgcn_mfma_f32_16x16x32_f16(a, b, c, 0, 0, 0)
#define MFMA32_F16(a, b, c) __builtin_amdgcn_mfma_f32_32x32x16_f16(a, b, c, 0, 0, 0)

#define LOG2_10K_32 0.41524101186092025f   // log2(10000)/32

__device__ __forceinline__ uint32_t swz(uint32_t ci) {
    return (ci & ~7u) | ((ci ^ (ci >> 3)) & 7u);
}

__device__ __forceinline__ void async_ld16(void* lds, const void* g) {
    __builtin_amdgcn_global_load_lds(
        (const __attribute__((address_space(1))) void*)g,
        (__attribute__((address_space(3))) void*)lds, 16, 0, 0);
}

// ---------------------------------------------------------------- prep: both W transposes in one launch
__global__ __launch_bounds__(256) void k_prep_w(
        const float* __restrict__ Wqkv, const float* __restrict__ Wout,
        f16* __restrict__ WqkvT, f16* __restrict__ WoutT) {
    __shared__ float tile[32][33];
    int x = threadIdx.x & 31, y = threadIdx.x >> 5;
    int bx = blockIdx.x;
    const float* S;
    f16* D;
    int rows, cols, bxe;
    if (bx < 96) { S = Wqkv; D = WqkvT; rows = 1024; cols = 3072; bxe = bx; }
    else         { S = Wout; D = WoutT; rows = 1024; cols = 1024; bxe = bx - 96; }
    int c0 = bxe * 32, r0 = blockIdx.y * 32;
#pragma unroll
    for (int i = 0; i < 32; i += 8)
        tile[y + i][x] = S[(size_t)(r0 + y + i) * cols + c0 + x];
    __syncthreads();
#pragma unroll
    for (int i = 0; i < 32; i += 8)
        D[(size_t)(c0 + y + i) * rows + r0 + x] = (f16)tile[x][y + i];
}

// ---------------------------------------------------------------- prep: RMSNorm + pmpad in one launch
__global__ __launch_bounds__(256) void k_prep_x(
        const float* __restrict__ seq, const float* __restrict__ w, f16* __restrict__ X,
        const float* __restrict__ pm, f16* __restrict__ Kb, f16* __restrict__ Vt) {
    __shared__ float red[4];
    const int b = blockIdx.x, t = threadIdx.x;
    if (b < 16384) {
        // ---- RMSNorm row b
        const float4* sp = (const float4*)(seq + (size_t)b * 1024);
        float4 v = sp[t];
        float ss = v.x * v.x + v.y * v.y + v.z * v.z + v.w * v.w;
#pragma unroll
        for (int off = 32; off >= 1; off >>= 1) ss += __shfl_xor(ss, off, 64);
        if ((t & 63) == 0) red[t >> 6] = ss;
        __syncthreads();
        float tot = red[0] + red[1] + red[2] + red[3];
        float rs = rsqrtf(tot * (1.0f / 1024.0f) + 1.1920929e-07f);
        const float4* wp = (const float4*)w;
        float4 wv = wp[t];
        f16x4 o;
        o[0] = (f16)(v.x * rs * wv.x);
        o[1] = (f16)(v.y * rs * wv.y);
        o[2] = (f16)(v.z * rs * wv.z);
        o[3] = (f16)(v.w * rs * wv.w);
        *(f16x4*)(X + (size_t)b * 1024 + t * 4) = o;
    } else {
        // ---- pmpad for wh = b - 16384
        int wh = b - 16384, h = wh & 15;
        const float* pk = pm + (size_t)h * 1024;
        f16* kb = Kb + (size_t)wh * 36864;
        int e0 = t * 4;
#pragma unroll
        for (int k = 0; k < 4; k++) kb[e0 + k] = (f16)pk[e0 + k];
#pragma unroll
        for (int k = 0; k < 12; k++) kb[33792 + t + k * 256] = (f16)0.f;
        const float* pv = pm + 16384 + (size_t)h * 1024;
        f16* vb = Vt + (size_t)wh * 36864;
        {
            int d = t & 63, s4 = (t >> 6) * 4;
#pragma unroll
            for (int k = 0; k < 4; k++)
                vb[(size_t)d * 576 + s4 + k] = (f16)pv[(s4 + k) * 64 + d];
        }
        {
            int d = t >> 2, rep = t & 3;
#pragma unroll
            for (int m = 0; m < 12; m++)
                vb[(size_t)d * 576 + 528 + rep * 12 + m] = (f16)0.f;
        }
    }
}

// ---------------------------------------------------------------- QKV GEMM (r5 structure + inline RoPE: proven 156us)
__global__ __launch_bounds__(256) void k_gemm_qkv(
        const f16* __restrict__ A, const f16* __restrict__ BT,
        f16* __restrict__ Qb, f16* __restrict__ Kb, f16* __restrict__ Vt) {
    const int K = 1024;
    __shared__ f16 As[128 * 32];
    __shared__ f16 Bs[128 * 32];
    const int t = threadIdx.x;
    const int lane = t & 63, wave = t >> 6, l32 = lane & 31, half = lane >> 5;
    const int m0 = blockIdx.y * 128, n0 = blockIdx.x * 128;
    const int wm = (wave & 1) * 64, wn = (wave >> 1) * 64;
    f32x16 acc[2][2];
#pragma unroll
    for (int i = 0; i < 2; i++)
#pragma unroll
        for (int j = 0; j < 2; j++)
#pragma unroll
            for (int r = 0; r < 16; r++) acc[i][j][r] = 0.f;

    uint32_t aoff[2][2], boff[2][2];
#pragma unroll
    for (int bk = 0; bk < 2; bk++)
#pragma unroll
        for (int ks = 0; ks < 2; ks++) {
            aoff[bk][ks] = swz((uint32_t)(wm + bk * 32 + l32) * 4 + ks * 2 + half) * 16;
            boff[bk][ks] = swz((uint32_t)(wn + bk * 32 + l32) * 4 + ks * 2 + half) * 16;
        }
    uint32_t c0 = swz(t), c1 = swz(t + 256);
    const f16* Ag0 = A + (size_t)(m0 + (c0 >> 2)) * K + (c0 & 3) * 8;
    const f16* Ag1 = A + (size_t)(m0 + (c1 >> 2)) * K + (c1 & 3) * 8;
    const f16* Bg0 = BT + (size_t)(n0 + (c0 >> 2)) * K + (c0 & 3) * 8;
    const f16* Bg1 = BT + (size_t)(n0 + (c1 >> 2)) * K + (c1 & 3) * 8;
    char* AsB = (char*)As;
    char* BsB = (char*)Bs;

    for (int k0 = 0; k0 < K; k0 += 32) {
        __syncthreads();
        async_ld16(AsB + t * 16, Ag0 + k0);
        async_ld16(AsB + (t + 256) * 16, Ag1 + k0);
        async_ld16(BsB + t * 16, Bg0 + k0);
        async_ld16(BsB + (t + 256) * 16, Bg1 + k0);
        __builtin_amdgcn_s_waitcnt(0x0f70);  // vmcnt(0)
        __syncthreads();
        f16x8 a[2][2], b[2][2];
#pragma unroll
        for (int bk = 0; bk < 2; bk++)
#pragma unroll
            for (int ks = 0; ks < 2; ks++) {
                a[bk][ks] = *(const f16x8*)(AsB + aoff[bk][ks]);
                b[bk][ks] = *(const f16x8*)(BsB + boff[bk][ks]);
            }
#pragma unroll
        for (int mb = 0; mb < 2; mb++)
#pragma unroll
            for (int nb = 0; nb < 2; nb++) {
                acc[mb][nb] = MFMA32_F16(b[nb][0], a[mb][0], acc[mb][nb]);
                acc[mb][nb] = MFMA32_F16(b[nb][1], a[mb][1], acc[mb][nb]);
            }
    }

    // region uniform per block: 0=Q, 1=K, 2=V
    const int region = n0 >> 10;
#pragma unroll
    for (int mb = 0; mb < 2; mb++) {
        int row = m0 + wm + mb * 32 + l32;       // token 0..16383
        int b_ = row >> 13, n_ = row & 8191;
        int win = n_ >> 9, i_ = n_ & 511;
        float fn = (float)n_;
#pragma unroll
        for (int nb = 0; nb < 2; nb++) {
            int colb = n0 + wn + nb * 32 + half * 4;
            int cr = colb & 1023;                 // feature idx within region
            int h = cr >> 6;
            int d0 = cr & 63;                     // multiple of 4
            int wh = ((b_ * 16 + win) << 4) + h;
            if (region < 2) {
                f16* base = (region == 0)
                    ? (Qb + ((size_t)wh * 512 + i_) * 64)
                    : (Kb + ((size_t)wh * 576 + 16 + i_) * 64);
#pragma unroll
                for (int q = 0; q < 4; q++) {
                    int d = d0 + q * 8;
                    float j0f = (float)(d >> 1);
                    float ang0 = fn * exp2f(-LOG2_10K_32 * j0f);
                    float ang1 = fn * exp2f(-LOG2_10K_32 * (j0f + 1.0f));
                    float s0, c0f, s1, c1f;
                    sincosf(ang0, &s0, &c0f);
                    sincosf(ang1, &s1, &c1f);
                    float x0 = (float)(f16)acc[mb][nb][q * 4 + 0];
                    float x1 = (float)(f16)acc[mb][nb][q * 4 + 1];
                    float x2 = (float)(f16)acc[mb][nb][q * 4 + 2];
                    float x3 = (float)(f16)acc[mb][nb][q * 4 + 3];
                    f16x4 ov;
                    ov[0] = (f16)(x0 * c0f - x1 * s0);
                    ov[1] = (f16)(x1 * c0f + x0 * s0);
                    ov[2] = (f16)(x2 * c1f - x3 * s1);
                    ov[3] = (f16)(x3 * c1f + x2 * s1);
                    *(f16x4*)(base + d) = ov;
                }
            } else {
                f16* vbase = Vt + (size_t)wh * 36864 + 16 + i_;
#pragma unroll
                for (int q = 0; q < 4; q++)
#pragma unroll
                    for (int r = 0; r < 4; r++)
                        vbase[(size_t)(d0 + q * 8 + r) * 576] = (f16)acc[mb][nb][q * 4 + r];
            }
        }
    }
}

// ---------------------------------------------------------------- out GEMM
// R13: 256^2 8-wave ring-4 counted-vmcnt structure (R6's k_gemm_out, which
// passed correctness). Dense full-line f32 writes -> no R6-style epilogue
// write amplification. Steady state vmcnt(8); never 0 until drain tail.
__global__ __launch_bounds__(512, 2) void k_gemm_out(
        const f16* __restrict__ A, const f16* __restrict__ BT,
        float* __restrict__ C, int M, int N, int Kp) {
    const int K = 1024;
    const int NT = 32;
    __shared__ __align__(16) char ldsA[65536];
    __shared__ __align__(16) char ldsB[65536];
    const int t = threadIdx.x;
    const int lane = t & 63, wave = t >> 6, l32 = lane & 31, half = lane >> 5;
    const int m0 = blockIdx.y * 256, n0 = blockIdx.x * 256;
    const int wm = (wave >> 2) * 128, wn = (wave & 3) * 64;

    f32x16 acc[4][2];
#pragma unroll
    for (int i = 0; i < 4; i++)
#pragma unroll
        for (int j = 0; j < 2; j++)
#pragma unroll
            for (int r = 0; r < 16; r++) acc[i][j][r] = 0.f;

    uint32_t aoff[4][2], boff[2][2];
#pragma unroll
    for (int mb = 0; mb < 4; mb++)
#pragma unroll
        for (int ks = 0; ks < 2; ks++)
            aoff[mb][ks] = swz((uint32_t)(wm + mb * 32 + l32) * 4 + ks * 2 + half) * 16;
#pragma unroll
    for (int nb = 0; nb < 2; nb++)
#pragma unroll
        for (int ks = 0; ks < 2; ks++)
            boff[nb][ks] = swz((uint32_t)(wn + nb * 32 + l32) * 4 + ks * 2 + half) * 16;

    uint32_t g0 = swz((uint32_t)t), g1 = swz((uint32_t)t + 512);
    const f16* Ag0 = A + (size_t)(m0 + (g0 >> 2)) * K + (g0 & 3) * 8;
    const f16* Ag1 = A + (size_t)(m0 + (g1 >> 2)) * K + (g1 & 3) * 8;
    const f16* Bg0 = BT + (size_t)(n0 + (g0 >> 2)) * K + (g0 & 3) * 8;
    const f16* Bg1 = BT + (size_t)(n0 + (g1 >> 2)) * K + (g1 & 3) * 8;

#pragma unroll
    for (int p = 0; p < 3; ++p) {
        char* dA = ldsA + p * 16384;
        async_ld16(dA + t * 16, Ag0 + p * 32);
        async_ld16(dA + (t + 512) * 16, Ag1 + p * 32);
        char* dB = ldsB + p * 16384;
        async_ld16(dB + t * 16, Bg0 + p * 32);
        async_ld16(dB + (t + 512) * 16, Bg1 + p * 32);
    }
    __builtin_amdgcn_s_waitcnt(0x0f78);   // vmcnt(8)
    __builtin_amdgcn_s_barrier();
    __builtin_amdgcn_sched_barrier(0);

#pragma unroll 4
    for (int kt = 0; kt < NT; ++kt) {
        char* As_s = ldsA + (kt & 3) * 16384;
        char* Bs_s = ldsB + (kt & 3) * 16384;
        f16x8 a00 = *(const f16x8*)(As_s + aoff[0][0]);
        f16x8 a01 = *(const f16x8*)(As_s + aoff[0][1]);
        f16x8 a10 = *(const f16x8*)(As_s + aoff[1][0]);
        f16x8 a11 = *(const f16x8*)(As_s + aoff[1][1]);
        f16x8 b00 = *(const f16x8*)(Bs_s + boff[0][0]);
        f16x8 b01 = *(const f16x8*)(Bs_s + boff[0][1]);
        f16x8 b10 = *(const f16x8*)(Bs_s + boff[1][0]);
        f16x8 b11 = *(const f16x8*)(Bs_s + boff[1][1]);
        if (kt < NT - 3) {
            char* dA = ldsA + ((kt + 3) & 3) * 16384;
            async_ld16(dA + t * 16, Ag0 + (kt + 3) * 32);
            async_ld16(dA + (t + 512) * 16, Ag1 + (kt + 3) * 32);
        }
        __builtin_amdgcn_s_barrier();
        __builtin_amdgcn_s_setprio(1);
        acc[0][0] = MFMA32_F16(b00, a00, acc[0][0]);
        acc[0][0] = MFMA32_F16(b01, a01, acc[0][0]);
        acc[0][1] = MFMA32_F16(b10, a00, acc[0][1]);
        acc[0][1] = MFMA32_F16(b11, a01, acc[0][1]);
        acc[1][0] = MFMA32_F16(b00, a10, acc[1][0]);
        acc[1][0] = MFMA32_F16(b01, a11, acc[1][0]);
        acc[1][1] = MFMA32_F16(b10, a10, acc[1][1]);
        acc[1][1] = MFMA32_F16(b11, a11, acc[1][1]);
        __builtin_amdgcn_s_setprio(0);
        __builtin_amdgcn_s_barrier();
        f16x8 a20 = *(const f16x8*)(As_s + aoff[2][0]);
        f16x8 a21 = *(const f16x8*)(As_s + aoff[2][1]);
        f16x8 a30 = *(const f16x8*)(As_s + aoff[3][0]);
        f16x8 a31 = *(const f16x8*)(As_s + aoff[3][1]);
        if (kt < NT - 3) {
            char* dB = ldsB + ((kt + 3) & 3) * 16384;
            async_ld16(dB + t * 16, Bg0 + (kt + 3) * 32);
            async_ld16(dB + (t + 512) * 16, Bg1 + (kt + 3) * 32);
        }
        __builtin_amdgcn_s_barrier();
        __builtin_amdgcn_s_setprio(1);
        acc[2][0] = MFMA32_F16(b00, a20, acc[2][0]);
        acc[2][0] = MFMA32_F16(b01, a21, acc[2][0]);
        acc[2][1] = MFMA32_F16(b10, a20, acc[2][1]);
        acc[2][1] = MFMA32_F16(b11, a21, acc[2][1]);
        acc[3][0] = MFMA32_F16(b00, a30, acc[3][0]);
        acc[3][0] = MFMA32_F16(b01, a31, acc[3][0]);
        acc[3][1] = MFMA32_F16(b10, a30, acc[3][1]);
        acc[3][1] = MFMA32_F16(b11, a31, acc[3][1]);
        __builtin_amdgcn_s_setprio(0);
        if (kt < NT - 3)       __builtin_amdgcn_s_waitcnt(0x0f78);
        else if (kt == NT - 3) __builtin_amdgcn_s_waitcnt(0x0f74);
        else if (kt == NT - 2) __builtin_amdgcn_s_waitcnt(0x0f70);
        __builtin_amdgcn_s_barrier();
        __builtin_amdgcn_sched_barrier(0);
    }

#pragma unroll
    for (int mb = 0; mb < 4; mb++) {
        int row = m0 + wm + mb * 32 + l32;
#pragma unroll
        for (int nb = 0; nb < 2; nb++) {
            int colb = n0 + wn + nb * 32 + half * 4;
#pragma unroll
            for (int q = 0; q < 4; q++) {
                f32x4 ov;
#pragma unroll
                for (int r = 0; r < 4; r++) ov[r] = acc[mb][nb][q * 4 + r];
                *(f32x4*)(C + (size_t)row * N + colb + q * 8) = ov;
            }
        }
    }
    (void)M; (void)Kp;
}

// ---------------------------------------------------------------- attention (R11, unchanged)
__global__ __launch_bounds__(512) void k_attn(
        const f16* __restrict__ Q, const f16* __restrict__ Kb,
        const f16* __restrict__ Vt, f16* __restrict__ AO) {
    const int bid = blockIdx.x;
    const int wh = ((bid >> 5) << 3) | (bid & 7);   // bid = 32*(wh>>3) + 8*pair + (wh&7)
    const int pair = (bid >> 3) & 3;
    const int i0 = pair * 128;
    const int t = threadIdx.x, lane = t & 63, wave = t >> 6, quad = lane >> 4, l16 = lane & 15;
    __shared__ f16 Ks[64 * 64];
    __shared__ f16 Vs[64 * 64];
    __shared__ f16 Ps[8][16][80];

    const int ig = i0 + wave * 16 + l16;
    const f16* qptr = Q + ((size_t)wh * 512 + ig) * 64 + quad * 8;
    f16x8 qf0 = *(const f16x8*)(qptr);
    f16x8 qf1 = *(const f16x8*)(qptr + 32);

    const f32x4 zero = {0.f, 0.f, 0.f, 0.f};
    f32x4 o[4];
#pragma unroll
    for (int i = 0; i < 4; i++) o[i] = zero;
    float m_l = -1e30f, l_l = 0.f;

    uint32_t g = swz((uint32_t)t);                   // 512 granules, 1 load/thread
    const f16* kg0 = Kb + ((size_t)wh * 576 + (g >> 3)) * 64 + (g & 7) * 8;
    const f16* vg0 = Vt + ((size_t)wh * 64 + (g >> 3)) * 576 + (g & 7) * 8;
    char* KsB = (char*)Ks;
    char* VsB = (char*)Vs;

    uint32_t boff[4][2];
#pragma unroll
    for (int i = 0; i < 4; i++)
#pragma unroll
        for (int f = 0; f < 2; f++)
            boff[i][f] = swz((uint32_t)(i * 16 + l16) * 8 + f * 4 + quad) * 16;

    f16* psrow = &Ps[wave][l16][0];
    int njt = 2 * pair + 3;
    if (njt > 9) njt = 9;

    const int jcap = (ig + 16 < 527) ? (ig + 16) : 527;   // jg<=ig+16 && jg<528

    // prologue: load tile 0 into regs (pre-swizzled global addr, linear LDS dest)
    f16x8 kreg = *(const f16x8*)(kg0);
    f16x8 vreg = *(const f16x8*)(vg0);

    for (int jt = 0; jt < njt; jt++) {
        const int j0 = jt * 64;
        // B1: all waves done reading LDS of tile jt-1 (raw barrier: no vmcnt drain)
        __builtin_amdgcn_sched_barrier(0);
        __builtin_amdgcn_s_barrier();
        __builtin_amdgcn_sched_barrier(0);
        *(f16x8*)(KsB + t * 16) = kreg;
        *(f16x8*)(VsB + t * 16) = vreg;
        if (jt + 1 < njt) {
            kreg = *(const f16x8*)(kg0 + (size_t)(j0 + 64) * 64);
            vreg = *(const f16x8*)(vg0 + (j0 + 64));
        }
        // B2: this tile's LDS writes visible to all waves
        __builtin_amdgcn_s_waitcnt(0xc07f);  // lgkmcnt(0): own ds_writes done
        __builtin_amdgcn_sched_barrier(0);
        __builtin_amdgcn_s_barrier();
        __builtin_amdgcn_sched_barrier(0);

        f32x4 s[4];
#pragma unroll
        for (int jb = 0; jb < 4; jb++) {
            f16x8 kv0 = *(const f16x8*)(KsB + boff[jb][0]);
            f16x8 kv1 = *(const f16x8*)(KsB + boff[jb][1]);
            f32x4 z = zero;
            z = MFMA_F16(kv0, qf0, z);
            z = MFMA_F16(kv1, qf1, z);
            s[jb] = z;
        }

        // wave-uniform: tile fully unmasked for every lane of this wave?
        const bool fullt = (j0 + 63 <= i0 + wave * 16 + 16) && (j0 + 64 <= 528);
        float mx = -1e30f;
        if (fullt) {
#pragma unroll
            for (int jb = 0; jb < 4; jb++)
#pragma unroll
                for (int r = 0; r < 4; r++) {
                    float val = s[jb][r] * 0.125f;
                    s[jb][r] = val;
                    mx = fmaxf(mx, val);
                }
        } else {
#pragma unroll
            for (int jb = 0; jb < 4; jb++)
#pragma unroll
                for (int r = 0; r < 4; r++) {
                    int jg = j0 + jb * 16 + quad * 4 + r;
                    float val = (jg <= jcap) ? s[jb][r] * 0.125f : -1e30f;
                    s[jb][r] = val;
                    mx = fmaxf(mx, val);
                }
        }
        mx = fmaxf(mx, __shfl_xor(mx, 16, 64));
        mx = fmaxf(mx, __shfl_xor(mx, 32, 64));
        const bool skipresc = __all(mx <= m_l);        // -> mnew==m_l, alpha==1 exactly
        float mnew = fmaxf(m_l, mx);
        float alpha = 1.0f;
        if (!skipresc) alpha = __expf(m_l - mnew);
        m_l = mnew;
        float rsum = 0.f;
#pragma unroll
        for (int jb = 0; jb < 4; jb++) {
            f16x4 pw;
#pragma unroll
            for (int r = 0; r < 4; r++) {
                float p = __expf(s[jb][r] - mnew);
                rsum += p;
                pw[r] = (f16)p;
            }
            *(f16x4*)(psrow + jb * 16 + quad * 4) = pw;
        }
        rsum += __shfl_xor(rsum, 16, 64);
        rsum += __shfl_xor(rsum, 32, 64);
        if (skipresc) {
            l_l = l_l + rsum;                          // == l_l*1.0f + rsum bitwise
        } else {
            l_l = l_l * alpha + rsum;
#pragma unroll
            for (int nd = 0; nd < 4; nd++) o[nd] *= alpha;
        }

        // Ps is wave-local: wave-level DS completion suffices (no barrier)
        __builtin_amdgcn_s_waitcnt(0xc07f);  // lgkmcnt(0)
        __builtin_amdgcn_sched_barrier(0);

        f16x8 pb0 = *(const f16x8*)(psrow + quad * 8);
        f16x8 pb1 = *(const f16x8*)(psrow + 32 + quad * 8);
#pragma unroll
        for (int nd = 0; nd < 4; nd++) {
            f16x8 v0 = *(const f16x8*)(VsB + boff[nd][0]);
            f16x8 v1 = *(const f16x8*)(VsB + boff[nd][1]);
            o[nd] = MFMA_F16(v0, pb0, o[nd]);
            o[nd] = MFMA_F16(v1, pb1, o[nd]);
        }
    }

    const int bw = wh >> 4, h = wh & 15;
    float inv = 1.f / l_l;
    f16* dst = AO + ((size_t)bw * 512 + ig) * 1024 + h * 64 + quad * 4;
#pragma unroll
    for (int nd = 0; nd < 4; nd++) {
        f16x4 ov;
#pragma unroll
        for (int r = 0; r < 4; r++) ov[r] = (f16)(o[nd][r] * inv);
        *(f16x4*)(dst + nd * 16) = ov;
    }
}

// ---------------------------------------------------------------- launch
extern "C" void kernel_launch(void* const* d_in, const int* in_sizes, int n_in,
                              void* d_out, int out_size, void* d_ws, size_t ws_size,
                              hipStream_t stream) {
    const float* seq   = (const float*)d_in[0];
    const float* wnorm = (const float*)d_in[1];
    const float* Wqkv  = (const float*)d_in[2];
    const float* Wout  = (const float*)d_in[3];
    const float* pm    = (const float*)d_in[4];
    float* out = (float*)d_out;
    char* ws = (char*)d_ws;

    f16* WqkvT = (f16*)(ws + 0);            // 3072x1024  = 6 MB
    f16* WoutT = (f16*)(ws + 6291456);      // 1024x1024  = 2 MB
    f16* X     = (f16*)(ws + 8388608);      // 16384x1024 = 32 MB
    f16* Qb    = (f16*)(ws + 41943040);     // 512x512x64 = 32 MB
    f16* AO    = (f16*)(ws + 75497472);     // 16384x1024 = 32 MB
    f16* Kb    = (f16*)(ws + 109051904);    // 512x576x64 = 36 MB
    f16* Vt    = (f16*)(ws + 146800640);    // 512x64x576 = 36 MB  (end 176 MB)

    k_prep_w<<<dim3(128, 32), 256, 0, stream>>>(Wqkv, Wout, WqkvT, WoutT);
    k_prep_x<<<16896, 256, 0, stream>>>(seq, wnorm, X, pm, Kb, Vt);
    k_gemm_qkv<<<dim3(24, 128), 256, 0, stream>>>(X, WqkvT, Qb, Kb, Vt);
    k_attn<<<2048, 512, 0, stream>>>(Qb, Kb, Vt, AO);
    k_gemm_out<<<dim3(4, 64), 512, 0, stream>>>(AO, WoutT, out, 16384, 1024, 1024);
}

// Round 11
// 405.962 us; speedup vs baseline: 1.0449x; 1.0025x over previous
//
#include <hip/hip_runtime.h>
#include <hip/hip_bf16.h>
#include <stdint.h>
#include <stddef.h>

typedef _Float16 f16;
typedef __attribute__((ext_vector_type(8))) _Float16 f16x8;
typedef __attribute__((ext_vector_type(4))) _Float16 f16x4;
typedef __attribute__((ext_vector_type(4))) float f32x4;
typedef __attribute__((ext_vector_type(16))) float f32x16;

#define MFMA_F16(a, b, c) __builtin_amdgcn_mfma_f32_16x16x32_f16(a, b, c, 0, 0, 0)
#define MFMA32_F16(a, b, c) __builtin_amdgcn_mfma_f32_32x32x16_f16(a, b, c, 0, 0, 0)

#define LOG2_10K_32 0.41524101186092025f   // log2(10000)/32

__device__ __forceinline__ uint32_t swz(uint32_t ci) {
    return (ci & ~7u) | ((ci ^ (ci >> 3)) & 7u);
}

__device__ __forceinline__ void async_ld16(void* lds, const void* g) {
    __builtin_amdgcn_global_load_lds(
        (const __attribute__((address_space(1))) void*)g,
        (__attribute__((address_space(3))) void*)lds, 16, 0, 0);
}

// ---------------------------------------------------------------- prep: W transposes + RMSNorm + pmpad, ONE launch
// b < 4096            : W transpose tile (bx = b&127 -> Wqkv[<96]/Wout, y = b>>7)
// 4096 <= b < 20480   : RMSNorm row (b-4096)
// 20480 <= b < 20992  : pmpad wh = b-20480
__global__ __launch_bounds__(256) void k_prep(
        const float* __restrict__ Wqkv, const float* __restrict__ Wout,
        f16* __restrict__ WqkvT, f16* __restrict__ WoutT,
        const float* __restrict__ seq, const float* __restrict__ wnorm, f16* __restrict__ X,
        const float* __restrict__ pm, f16* __restrict__ Kb, f16* __restrict__ Vt) {
    __shared__ float tile[32][33];
    const int b = blockIdx.x, t = threadIdx.x;
    if (b < 4096) {
        int x = t & 31, y = t >> 5;
        int bx = b & 127, by = b >> 7;
        const float* S;
        f16* D;
        int rows, cols, bxe;
        if (bx < 96) { S = Wqkv; D = WqkvT; rows = 1024; cols = 3072; bxe = bx; }
        else         { S = Wout; D = WoutT; rows = 1024; cols = 1024; bxe = bx - 96; }
        int c0 = bxe * 32, r0 = by * 32;
#pragma unroll
        for (int i = 0; i < 32; i += 8)
            tile[y + i][x] = S[(size_t)(r0 + y + i) * cols + c0 + x];
        __syncthreads();
#pragma unroll
        for (int i = 0; i < 32; i += 8)
            D[(size_t)(c0 + y + i) * rows + r0 + x] = (f16)tile[x][y + i];
    } else if (b < 20480) {
        // ---- RMSNorm row
        int row = b - 4096;
        float* red = &tile[0][0];
        const float4* sp = (const float4*)(seq + (size_t)row * 1024);
        float4 v = sp[t];
        float ss = v.x * v.x + v.y * v.y + v.z * v.z + v.w * v.w;
#pragma unroll
        for (int off = 32; off >= 1; off >>= 1) ss += __shfl_xor(ss, off, 64);
        if ((t & 63) == 0) red[t >> 6] = ss;
        __syncthreads();
        float tot = red[0] + red[1] + red[2] + red[3];
        float rs = rsqrtf(tot * (1.0f / 1024.0f) + 1.1920929e-07f);
        const float4* wp = (const float4*)wnorm;
        float4 wv = wp[t];
        f16x4 o;
        o[0] = (f16)(v.x * rs * wv.x);
        o[1] = (f16)(v.y * rs * wv.y);
        o[2] = (f16)(v.z * rs * wv.z);
        o[3] = (f16)(v.w * rs * wv.w);
        *(f16x4*)(X + (size_t)row * 1024 + t * 4) = o;
    } else {
        // ---- pmpad
        int wh = b - 20480, h = wh & 15;
        const float* pk = pm + (size_t)h * 1024;
        f16* kb = Kb + (size_t)wh * 36864;
        int e0 = t * 4;
#pragma unroll
        for (int k = 0; k < 4; k++) kb[e0 + k] = (f16)pk[e0 + k];
#pragma unroll
        for (int k = 0; k < 12; k++) kb[33792 + t + k * 256] = (f16)0.f;
        const float* pv = pm + 16384 + (size_t)h * 1024;
        f16* vb = Vt + (size_t)wh * 36864;
        {
            int d = t & 63, s4 = (t >> 6) * 4;
#pragma unroll
            for (int k = 0; k < 4; k++)
                vb[(size_t)d * 576 + s4 + k] = (f16)pv[(s4 + k) * 64 + d];
        }
        {
            int d = t >> 2, rep = t & 3;
#pragma unroll
            for (int m = 0; m < 12; m++)
                vb[(size_t)d * 576 + 528 + rep * 12 + m] = (f16)0.f;
        }
    }
}

// ---------------------------------------------------------------- QKV GEMM (r5 structure + inline RoPE: proven 156us)
__global__ __launch_bounds__(256) void k_gemm_qkv(
        const f16* __restrict__ A, const f16* __restrict__ BT,
        f16* __restrict__ Qb, f16* __restrict__ Kb, f16* __restrict__ Vt) {
    const int K = 1024;
    __shared__ f16 As[128 * 32];
    __shared__ f16 Bs[128 * 32];
    const int t = threadIdx.x;
    const int lane = t & 63, wave = t >> 6, l32 = lane & 31, half = lane >> 5;
    const int m0 = blockIdx.y * 128, n0 = blockIdx.x * 128;
    const int wm = (wave & 1) * 64, wn = (wave >> 1) * 64;
    f32x16 acc[2][2];
#pragma unroll
    for (int i = 0; i < 2; i++)
#pragma unroll
        for (int j = 0; j < 2; j++)
#pragma unroll
            for (int r = 0; r < 16; r++) acc[i][j][r] = 0.f;

    uint32_t aoff[2][2], boff[2][2];
#pragma unroll
    for (int bk = 0; bk < 2; bk++)
#pragma unroll
        for (int ks = 0; ks < 2; ks++) {
            aoff[bk][ks] = swz((uint32_t)(wm + bk * 32 + l32) * 4 + ks * 2 + half) * 16;
            boff[bk][ks] = swz((uint32_t)(wn + bk * 32 + l32) * 4 + ks * 2 + half) * 16;
        }
    uint32_t c0 = swz(t), c1 = swz(t + 256);
    const f16* Ag0 = A + (size_t)(m0 + (c0 >> 2)) * K + (c0 & 3) * 8;
    const f16* Ag1 = A + (size_t)(m0 + (c1 >> 2)) * K + (c1 & 3) * 8;
    const f16* Bg0 = BT + (size_t)(n0 + (c0 >> 2)) * K + (c0 & 3) * 8;
    const f16* Bg1 = BT + (size_t)(n0 + (c1 >> 2)) * K + (c1 & 3) * 8;
    char* AsB = (char*)As;
    char* BsB = (char*)Bs;

    for (int k0 = 0; k0 < K; k0 += 32) {
        __syncthreads();
        async_ld16(AsB + t * 16, Ag0 + k0);
        async_ld16(AsB + (t + 256) * 16, Ag1 + k0);
        async_ld16(BsB + t * 16, Bg0 + k0);
        async_ld16(BsB + (t + 256) * 16, Bg1 + k0);
        __builtin_amdgcn_s_waitcnt(0x0f70);  // vmcnt(0)
        __syncthreads();
        f16x8 a[2][2], b[2][2];
#pragma unroll
        for (int bk = 0; bk < 2; bk++)
#pragma unroll
            for (int ks = 0; ks < 2; ks++) {
                a[bk][ks] = *(const f16x8*)(AsB + aoff[bk][ks]);
                b[bk][ks] = *(const f16x8*)(BsB + boff[bk][ks]);
            }
#pragma unroll
        for (int mb = 0; mb < 2; mb++)
#pragma unroll
            for (int nb = 0; nb < 2; nb++) {
                acc[mb][nb] = MFMA32_F16(b[nb][0], a[mb][0], acc[mb][nb]);
                acc[mb][nb] = MFMA32_F16(b[nb][1], a[mb][1], acc[mb][nb]);
            }
    }

    // region uniform per block: 0=Q, 1=K, 2=V
    const int region = n0 >> 10;
#pragma unroll
    for (int mb = 0; mb < 2; mb++) {
        int row = m0 + wm + mb * 32 + l32;       // token 0..16383
        int b_ = row >> 13, n_ = row & 8191;
        int win = n_ >> 9, i_ = n_ & 511;
        float fn = (float)n_;
#pragma unroll
        for (int nb = 0; nb < 2; nb++) {
            int colb = n0 + wn + nb * 32 + half * 4;
            int cr = colb & 1023;                 // feature idx within region
            int h = cr >> 6;
            int d0 = cr & 63;                     // multiple of 4
            int wh = ((b_ * 16 + win) << 4) + h;
            if (region < 2) {
                f16* base = (region == 0)
                    ? (Qb + ((size_t)wh * 512 + i_) * 64)
                    : (Kb + ((size_t)wh * 576 + 16 + i_) * 64);
#pragma unroll
                for (int q = 0; q < 4; q++) {
                    int d = d0 + q * 8;
                    float j0f = (float)(d >> 1);
                    float ang0 = fn * exp2f(-LOG2_10K_32 * j0f);
                    float ang1 = fn * exp2f(-LOG2_10K_32 * (j0f + 1.0f));
                    float s0, c0f, s1, c1f;
                    sincosf(ang0, &s0, &c0f);
                    sincosf(ang1, &s1, &c1f);
                    float x0 = (float)(f16)acc[mb][nb][q * 4 + 0];
                    float x1 = (float)(f16)acc[mb][nb][q * 4 + 1];
                    float x2 = (float)(f16)acc[mb][nb][q * 4 + 2];
                    float x3 = (float)(f16)acc[mb][nb][q * 4 + 3];
                    f16x4 ov;
                    ov[0] = (f16)(x0 * c0f - x1 * s0);
                    ov[1] = (f16)(x1 * c0f + x0 * s0);
                    ov[2] = (f16)(x2 * c1f - x3 * s1);
                    ov[3] = (f16)(x3 * c1f + x2 * s1);
                    *(f16x4*)(base + d) = ov;
                }
            } else {
                f16* vbase = Vt + (size_t)wh * 36864 + 16 + i_;
#pragma unroll
                for (int q = 0; q < 4; q++)
#pragma unroll
                    for (int r = 0; r < 4; r++)
                        vbase[(size_t)(d0 + q * 8 + r) * 576] = (f16)acc[mb][nb][q * 4 + r];
            }
        }
    }
}

// ---------------------------------------------------------------- out GEMM (256^2 ring-4 counted-vmcnt; confirmed ~25us)
__global__ __launch_bounds__(512, 2) void k_gemm_out(
        const f16* __restrict__ A, const f16* __restrict__ BT,
        float* __restrict__ C, int M, int N, int Kp) {
    const int K = 1024;
    const int NT = 32;
    __shared__ __align__(16) char ldsA[65536];
    __shared__ __align__(16) char ldsB[65536];
    const int t = threadIdx.x;
    const int lane = t & 63, wave = t >> 6, l32 = lane & 31, half = lane >> 5;
    const int m0 = blockIdx.y * 256, n0 = blockIdx.x * 256;
    const int wm = (wave >> 2) * 128, wn = (wave & 3) * 64;

    f32x16 acc[4][2];
#pragma unroll
    for (int i = 0; i < 4; i++)
#pragma unroll
        for (int j = 0; j < 2; j++)
#pragma unroll
            for (int r = 0; r < 16; r++) acc[i][j][r] = 0.f;

    uint32_t aoff[4][2], boff[2][2];
#pragma unroll
    for (int mb = 0; mb < 4; mb++)
#pragma unroll
        for (int ks = 0; ks < 2; ks++)
            aoff[mb][ks] = swz((uint32_t)(wm + mb * 32 + l32) * 4 + ks * 2 + half) * 16;
#pragma unroll
    for (int nb = 0; nb < 2; nb++)
#pragma unroll
        for (int ks = 0; ks < 2; ks++)
            boff[nb][ks] = swz((uint32_t)(wn + nb * 32 + l32) * 4 + ks * 2 + half) * 16;

    uint32_t g0 = swz((uint32_t)t), g1 = swz((uint32_t)t + 512);
    const f16* Ag0 = A + (size_t)(m0 + (g0 >> 2)) * K + (g0 & 3) * 8;
    const f16* Ag1 = A + (size_t)(m0 + (g1 >> 2)) * K + (g1 & 3) * 8;
    const f16* Bg0 = BT + (size_t)(n0 + (g0 >> 2)) * K + (g0 & 3) * 8;
    const f16* Bg1 = BT + (size_t)(n0 + (g1 >> 2)) * K + (g1 & 3) * 8;

#pragma unroll
    for (int p = 0; p < 3; ++p) {
        char* dA = ldsA + p * 16384;
        async_ld16(dA + t * 16, Ag0 + p * 32);
        async_ld16(dA + (t + 512) * 16, Ag1 + p * 32);
        char* dB = ldsB + p * 16384;
        async_ld16(dB + t * 16, Bg0 + p * 32);
        async_ld16(dB + (t + 512) * 16, Bg1 + p * 32);
    }
    __builtin_amdgcn_s_waitcnt(0x0f78);   // vmcnt(8)
    __builtin_amdgcn_s_barrier();
    __builtin_amdgcn_sched_barrier(0);

#pragma unroll 4
    for (int kt = 0; kt < NT; ++kt) {
        char* As_s = ldsA + (kt & 3) * 16384;
        char* Bs_s = ldsB + (kt & 3) * 16384;
        f16x8 a00 = *(const f16x8*)(As_s + aoff[0][0]);
        f16x8 a01 = *(const f16x8*)(As_s + aoff[0][1]);
        f16x8 a10 = *(const f16x8*)(As_s + aoff[1][0]);
        f16x8 a11 = *(const f16x8*)(As_s + aoff[1][1]);
        f16x8 b00 = *(const f16x8*)(Bs_s + boff[0][0]);
        f16x8 b01 = *(const f16x8*)(Bs_s + boff[0][1]);
        f16x8 b10 = *(const f16x8*)(Bs_s + boff[1][0]);
        f16x8 b11 = *(const f16x8*)(Bs_s + boff[1][1]);
        if (kt < NT - 3) {
            char* dA = ldsA + ((kt + 3) & 3) * 16384;
            async_ld16(dA + t * 16, Ag0 + (kt + 3) * 32);
            async_ld16(dA + (t + 512) * 16, Ag1 + (kt + 3) * 32);
        }
        __builtin_amdgcn_s_barrier();
        __builtin_amdgcn_s_setprio(1);
        acc[0][0] = MFMA32_F16(b00, a00, acc[0][0]);
        acc[0][0] = MFMA32_F16(b01, a01, acc[0][0]);
        acc[0][1] = MFMA32_F16(b10, a00, acc[0][1]);
        acc[0][1] = MFMA32_F16(b11, a01, acc[0][1]);
        acc[1][0] = MFMA32_F16(b00, a10, acc[1][0]);
        acc[1][0] = MFMA32_F16(b01, a11, acc[1][0]);
        acc[1][1] = MFMA32_F16(b10, a10, acc[1][1]);
        acc[1][1] = MFMA32_F16(b11, a11, acc[1][1]);
        __builtin_amdgcn_s_setprio(0);
        __builtin_amdgcn_s_barrier();
        f16x8 a20 = *(const f16x8*)(As_s + aoff[2][0]);
        f16x8 a21 = *(const f16x8*)(As_s + aoff[2][1]);
        f16x8 a30 = *(const f16x8*)(As_s + aoff[3][0]);
        f16x8 a31 = *(const f16x8*)(As_s + aoff[3][1]);
        if (kt < NT - 3) {
            char* dB = ldsB + ((kt + 3) & 3) * 16384;
            async_ld16(dB + t * 16, Bg0 + (kt + 3) * 32);
            async_ld16(dB + (t + 512) * 16, Bg1 + (kt + 3) * 32);
        }
        __builtin_amdgcn_s_barrier();
        __builtin_amdgcn_s_setprio(1);
        acc[2][0] = MFMA32_F16(b00, a20, acc[2][0]);
        acc[2][0] = MFMA32_F16(b01, a21, acc[2][0]);
        acc[2][1] = MFMA32_F16(b10, a20, acc[2][1]);
        acc[2][1] = MFMA32_F16(b11, a21, acc[2][1]);
        acc[3][0] = MFMA32_F16(b00, a30, acc[3][0]);
        acc[3][0] = MFMA32_F16(b01, a31, acc[3][0]);
        acc[3][1] = MFMA32_F16(b10, a30, acc[3][1]);
        acc[3][1] = MFMA32_F16(b11, a31, acc[3][1]);
        __builtin_amdgcn_s_setprio(0);
        if (kt < NT - 3)       __builtin_amdgcn_s_waitcnt(0x0f78);
        else if (kt == NT - 3) __builtin_amdgcn_s_waitcnt(0x0f74);
        else if (kt == NT - 2) __builtin_amdgcn_s_waitcnt(0x0f70);
        __builtin_amdgcn_s_barrier();
        __builtin_amdgcn_sched_barrier(0);
    }

#pragma unroll
    for (int mb = 0; mb < 4; mb++) {
        int row = m0 + wm + mb * 32 + l32;
#pragma unroll
        for (int nb = 0; nb < 2; nb++) {
            int colb = n0 + wn + nb * 32 + half * 4;
#pragma unroll
            for (int q = 0; q < 4; q++) {
                f32x4 ov;
#pragma unroll
                for (int r = 0; r < 4; r++) ov[r] = acc[mb][nb][q * 4 + r];
                *(f32x4*)(C + (size_t)row * N + colb + q * 8) = ov;
            }
        }
    }
    (void)M; (void)Kp;
}

// ---------------------------------------------------------------- attention (R11, unchanged)
__global__ __launch_bounds__(512) void k_attn(
        const f16* __restrict__ Q, const f16* __restrict__ Kb,
        const f16* __restrict__ Vt, f16* __restrict__ AO) {
    const int bid = blockIdx.x;
    const int wh = ((bid >> 5) << 3) | (bid & 7);   // bid = 32*(wh>>3) + 8*pair + (wh&7)
    const int pair = (bid >> 3) & 3;
    const int i0 = pair * 128;
    const int t = threadIdx.x, lane = t & 63, wave = t >> 6, quad = lane >> 4, l16 = lane & 15;
    __shared__ f16 Ks[64 * 64];
    __shared__ f16 Vs[64 * 64];
    __shared__ f16 Ps[8][16][80];

    const int ig = i0 + wave * 16 + l16;
    const f16* qptr = Q + ((size_t)wh * 512 + ig) * 64 + quad * 8;
    f16x8 qf0 = *(const f16x8*)(qptr);
    f16x8 qf1 = *(const f16x8*)(qptr + 32);

    const f32x4 zero = {0.f, 0.f, 0.f, 0.f};
    f32x4 o[4];
#pragma unroll
    for (int i = 0; i < 4; i++) o[i] = zero;
    float m_l = -1e30f, l_l = 0.f;

    uint32_t g = swz((uint32_t)t);                   // 512 granules, 1 load/thread
    const f16* kg0 = Kb + ((size_t)wh * 576 + (g >> 3)) * 64 + (g & 7) * 8;
    const f16* vg0 = Vt + ((size_t)wh * 64 + (g >> 3)) * 576 + (g & 7) * 8;
    char* KsB = (char*)Ks;
    char* VsB = (char*)Vs;

    uint32_t boff[4][2];
#pragma unroll
    for (int i = 0; i < 4; i++)
#pragma unroll
        for (int f = 0; f < 2; f++)
            boff[i][f] = swz((uint32_t)(i * 16 + l16) * 8 + f * 4 + quad) * 16;

    f16* psrow = &Ps[wave][l16][0];
    int njt = 2 * pair + 3;
    if (njt > 9) njt = 9;

    const int jcap = (ig + 16 < 527) ? (ig + 16) : 527;   // jg<=ig+16 && jg<528

    // prologue: load tile 0 into regs (pre-swizzled global addr, linear LDS dest)
    f16x8 kreg = *(const f16x8*)(kg0);
    f16x8 vreg = *(const f16x8*)(vg0);

    for (int jt = 0; jt < njt; jt++) {
        const int j0 = jt * 64;
        // B1: all waves done reading LDS of tile jt-1 (raw barrier: no vmcnt drain)
        __builtin_amdgcn_sched_barrier(0);
        __builtin_amdgcn_s_barrier();
        __builtin_amdgcn_sched_barrier(0);
        *(f16x8*)(KsB + t * 16) = kreg;
        *(f16x8*)(VsB + t * 16) = vreg;
        if (jt + 1 < njt) {
            kreg = *(const f16x8*)(kg0 + (size_t)(j0 + 64) * 64);
            vreg = *(const f16x8*)(vg0 + (j0 + 64));
        }
        // B2: this tile's LDS writes visible to all waves
        __builtin_amdgcn_s_waitcnt(0xc07f);  // lgkmcnt(0): own ds_writes done
        __builtin_amdgcn_sched_barrier(0);
        __builtin_amdgcn_s_barrier();
        __builtin_amdgcn_sched_barrier(0);

        f32x4 s[4];
#pragma unroll
        for (int jb = 0; jb < 4; jb++) {
            f16x8 kv0 = *(const f16x8*)(KsB + boff[jb][0]);
            f16x8 kv1 = *(const f16x8*)(KsB + boff[jb][1]);
            f32x4 z = zero;
            z = MFMA_F16(kv0, qf0, z);
            z = MFMA_F16(kv1, qf1, z);
            s[jb] = z;
        }

        // wave-uniform: tile fully unmasked for every lane of this wave?
        const bool fullt = (j0 + 63 <= i0 + wave * 16 + 16) && (j0 + 64 <= 528);
        float mx = -1e30f;
        if (fullt) {
#pragma unroll
            for (int jb = 0; jb < 4; jb++)
#pragma unroll
                for (int r = 0; r < 4; r++) {
                    float val = s[jb][r] * 0.125f;
                    s[jb][r] = val;
                    mx = fmaxf(mx, val);
                }
        } else {
#pragma unroll
            for (int jb = 0; jb < 4; jb++)
#pragma unroll
                for (int r = 0; r < 4; r++) {
                    int jg = j0 + jb * 16 + quad * 4 + r;
                    float val = (jg <= jcap) ? s[jb][r] * 0.125f : -1e30f;
                    s[jb][r] = val;
                    mx = fmaxf(mx, val);
                }
        }
        mx = fmaxf(mx, __shfl_xor(mx, 16, 64));
        mx = fmaxf(mx, __shfl_xor(mx, 32, 64));
        const bool skipresc = __all(mx <= m_l);        // -> mnew==m_l, alpha==1 exactly
        float mnew = fmaxf(m_l, mx);
        float alpha = 1.0f;
        if (!skipresc) alpha = __expf(m_l - mnew);
        m_l = mnew;
        float rsum = 0.f;
#pragma unroll
        for (int jb = 0; jb < 4; jb++) {
            f16x4 pw;
#pragma unroll
            for (int r = 0; r < 4; r++) {
                float p = __expf(s[jb][r] - mnew);
                rsum += p;
                pw[r] = (f16)p;
            }
            *(f16x4*)(psrow + jb * 16 + quad * 4) = pw;
        }
        rsum += __shfl_xor(rsum, 16, 64);
        rsum += __shfl_xor(rsum, 32, 64);
        if (skipresc) {
            l_l = l_l + rsum;                          // == l_l*1.0f + rsum bitwise
        } else {
            l_l = l_l * alpha + rsum;
#pragma unroll
            for (int nd = 0; nd < 4; nd++) o[nd] *= alpha;
        }

        // Ps is wave-local: wave-level DS completion suffices (no barrier)
        __builtin_amdgcn_s_waitcnt(0xc07f);  // lgkmcnt(0)
        __builtin_amdgcn_sched_barrier(0);

        f16x8 pb0 = *(const f16x8*)(psrow + quad * 8);
        f16x8 pb1 = *(const f16x8*)(psrow + 32 + quad * 8);
#pragma unroll
        for (int nd = 0; nd < 4; nd++) {
            f16x8 v0 = *(const f16x8*)(VsB + boff[nd][0]);
            f16x8 v1 = *(const f16x8*)(VsB + boff[nd][1]);
            o[nd] = MFMA_F16(v0, pb0, o[nd]);
            o[nd] = MFMA_F16(v1, pb1, o[nd]);
        }
    }

    const int bw = wh >> 4, h = wh & 15;
    float inv = 1.f / l_l;
    f16* dst = AO + ((size_t)bw * 512 + ig) * 1024 + h * 64 + quad * 4;
#pragma unroll
    for (int nd = 0; nd < 4; nd++) {
        f16x4 ov;
#pragma unroll
        for (int r = 0; r < 4; r++) ov[r] = (f16)(o[nd][r] * inv);
        *(f16x4*)(dst + nd * 16) = ov;
    }
}

// ---------------------------------------------------------------- launch
extern "C" void kernel_launch(void* const* d_in, const int* in_sizes, int n_in,
                              void* d_out, int out_size, void* d_ws, size_t ws_size,
                              hipStream_t stream) {
    const float* seq   = (const float*)d_in[0];
    const float* wnorm = (const float*)d_in[1];
    const float* Wqkv  = (const float*)d_in[2];
    const float* Wout  = (const float*)d_in[3];
    const float* pm    = (const float*)d_in[4];
    float* out = (float*)d_out;
    char* ws = (char*)d_ws;

    f16* WqkvT = (f16*)(ws + 0);            // 3072x1024  = 6 MB
    f16* WoutT = (f16*)(ws + 6291456);      // 1024x1024  = 2 MB
    f16* X     = (f16*)(ws + 8388608);      // 16384x1024 = 32 MB
    f16* Qb    = (f16*)(ws + 41943040);     // 512x512x64 = 32 MB
    f16* AO    = (f16*)(ws + 75497472);     // 16384x1024 = 32 MB
    f16* Kb    = (f16*)(ws + 109051904);    // 512x576x64 = 36 MB
    f16* Vt    = (f16*)(ws + 146800640);    // 512x64x576 = 36 MB  (end 176 MB)

    k_prep<<<20992, 256, 0, stream>>>(Wqkv, Wout, WqkvT, WoutT, seq, wnorm, X, pm, Kb, Vt);
    k_gemm_qkv<<<dim3(24, 128), 256, 0, stream>>>(X, WqkvT, Qb, Kb, Vt);
    k_attn<<<2048, 512, 0, stream>>>(Qb, Kb, Vt, AO);
    k_gemm_out<<<dim3(4, 64), 512, 0, stream>>>(AO, WoutT, out, 16384, 1024, 1024);
}

// Round 12
// 399.842 us; speedup vs baseline: 1.0609x; 1.0153x over previous
//
#include <hip/hip_runtime.h>
#include <hip/hip_bf16.h>
#include <stdint.h>
#include <stddef.h>

typedef _Float16 f16;
typedef __attribute__((ext_vector_type(8))) _Float16 f16x8;
typedef __attribute__((ext_vector_type(4))) _Float16 f16x4;
typedef __attribute__((ext_vector_type(4))) float f32x4;
typedef __attribute__((ext_vector_type(16))) float f32x16;

#define MFMA_F16(a, b, c) __builtin_amdgcn_mfma_f32_16x16x32_f16(a, b, c, 0, 0, 0)
#define MFMA32_F16(a, b, c) __builtin_amdgcn_mfma_f32_32x32x16_f16(a, b, c, 0, 0, 0)

#define LOG2_10K_32 0.41524101186092025f   // log2(10000)/32

__device__ __forceinline__ uint32_t swz(uint32_t ci) {
    return (ci & ~7u) | ((ci ^ (ci >> 3)) & 7u);
}

__device__ __forceinline__ void async_ld16(void* lds, const void* g) {
    __builtin_amdgcn_global_load_lds(
        (const __attribute__((address_space(1))) void*)g,
        (__attribute__((address_space(3))) void*)lds, 16, 0, 0);
}

// ---------------------------------------------------------------- prep: W transposes + RMSNorm + pmpad, ONE launch
__global__ __launch_bounds__(256) void k_prep(
        const float* __restrict__ Wqkv, const float* __restrict__ Wout,
        f16* __restrict__ WqkvT, f16* __restrict__ WoutT,
        const float* __restrict__ seq, const float* __restrict__ wnorm, f16* __restrict__ X,
        const float* __restrict__ pm, f16* __restrict__ Kb, f16* __restrict__ Vt) {
    __shared__ float tile[32][33];
    const int b = blockIdx.x, t = threadIdx.x;
    if (b < 4096) {
        int x = t & 31, y = t >> 5;
        int bx = b & 127, by = b >> 7;
        const float* S;
        f16* D;
        int rows, cols, bxe;
        if (bx < 96) { S = Wqkv; D = WqkvT; rows = 1024; cols = 3072; bxe = bx; }
        else         { S = Wout; D = WoutT; rows = 1024; cols = 1024; bxe = bx - 96; }
        int c0 = bxe * 32, r0 = by * 32;
#pragma unroll
        for (int i = 0; i < 32; i += 8)
            tile[y + i][x] = S[(size_t)(r0 + y + i) * cols + c0 + x];
        __syncthreads();
#pragma unroll
        for (int i = 0; i < 32; i += 8)
            D[(size_t)(c0 + y + i) * rows + r0 + x] = (f16)tile[x][y + i];
    } else if (b < 20480) {
        // ---- RMSNorm row
        int row = b - 4096;
        float* red = &tile[0][0];
        const float4* sp = (const float4*)(seq + (size_t)row * 1024);
        float4 v = sp[t];
        float ss = v.x * v.x + v.y * v.y + v.z * v.z + v.w * v.w;
#pragma unroll
        for (int off = 32; off >= 1; off >>= 1) ss += __shfl_xor(ss, off, 64);
        if ((t & 63) == 0) red[t >> 6] = ss;
        __syncthreads();
        float tot = red[0] + red[1] + red[2] + red[3];
        float rs = rsqrtf(tot * (1.0f / 1024.0f) + 1.1920929e-07f);
        const float4* wp = (const float4*)wnorm;
        float4 wv = wp[t];
        f16x4 o;
        o[0] = (f16)(v.x * rs * wv.x);
        o[1] = (f16)(v.y * rs * wv.y);
        o[2] = (f16)(v.z * rs * wv.z);
        o[3] = (f16)(v.w * rs * wv.w);
        *(f16x4*)(X + (size_t)row * 1024 + t * 4) = o;
    } else {
        // ---- pmpad
        int wh = b - 20480, h = wh & 15;
        const float* pk = pm + (size_t)h * 1024;
        f16* kb = Kb + (size_t)wh * 36864;
        int e0 = t * 4;
#pragma unroll
        for (int k = 0; k < 4; k++) kb[e0 + k] = (f16)pk[e0 + k];
#pragma unroll
        for (int k = 0; k < 12; k++) kb[33792 + t + k * 256] = (f16)0.f;
        const float* pv = pm + 16384 + (size_t)h * 1024;
        f16* vb = Vt + (size_t)wh * 36864;
        {
            int d = t & 63, s4 = (t >> 6) * 4;
#pragma unroll
            for (int k = 0; k < 4; k++)
                vb[(size_t)d * 576 + s4 + k] = (f16)pv[(s4 + k) * 64 + d];
        }
        {
            int d = t >> 2, rep = t & 3;
#pragma unroll
            for (int m = 0; m < 12; m++)
                vb[(size_t)d * 576 + 528 + rep * 12 + m] = (f16)0.f;
        }
    }
}

// ---------------------------------------------------------------- QKV GEMM (r5 structure + inline RoPE: proven 156us)
__global__ __launch_bounds__(256) void k_gemm_qkv(
        const f16* __restrict__ A, const f16* __restrict__ BT,
        f16* __restrict__ Qb, f16* __restrict__ Kb, f16* __restrict__ Vt) {
    const int K = 1024;
    __shared__ f16 As[128 * 32];
    __shared__ f16 Bs[128 * 32];
    const int t = threadIdx.x;
    const int lane = t & 63, wave = t >> 6, l32 = lane & 31, half = lane >> 5;
    const int m0 = blockIdx.y * 128, n0 = blockIdx.x * 128;
    const int wm = (wave & 1) * 64, wn = (wave >> 1) * 64;
    f32x16 acc[2][2];
#pragma unroll
    for (int i = 0; i < 2; i++)
#pragma unroll
        for (int j = 0; j < 2; j++)
#pragma unroll
            for (int r = 0; r < 16; r++) acc[i][j][r] = 0.f;

    uint32_t aoff[2][2], boff[2][2];
#pragma unroll
    for (int bk = 0; bk < 2; bk++)
#pragma unroll
        for (int ks = 0; ks < 2; ks++) {
            aoff[bk][ks] = swz((uint32_t)(wm + bk * 32 + l32) * 4 + ks * 2 + half) * 16;
            boff[bk][ks] = swz((uint32_t)(wn + bk * 32 + l32) * 4 + ks * 2 + half) * 16;
        }
    uint32_t c0 = swz(t), c1 = swz(t + 256);
    const f16* Ag0 = A + (size_t)(m0 + (c0 >> 2)) * K + (c0 & 3) * 8;
    const f16* Ag1 = A + (size_t)(m0 + (c1 >> 2)) * K + (c1 & 3) * 8;
    const f16* Bg0 = BT + (size_t)(n0 + (c0 >> 2)) * K + (c0 & 3) * 8;
    const f16* Bg1 = BT + (size_t)(n0 + (c1 >> 2)) * K + (c1 & 3) * 8;
    char* AsB = (char*)As;
    char* BsB = (char*)Bs;

    for (int k0 = 0; k0 < K; k0 += 32) {
        __syncthreads();
        async_ld16(AsB + t * 16, Ag0 + k0);
        async_ld16(AsB + (t + 256) * 16, Ag1 + k0);
        async_ld16(BsB + t * 16, Bg0 + k0);
        async_ld16(BsB + (t + 256) * 16, Bg1 + k0);
        __builtin_amdgcn_s_waitcnt(0x0f70);  // vmcnt(0)
        __syncthreads();
        f16x8 a[2][2], b[2][2];
#pragma unroll
        for (int bk = 0; bk < 2; bk++)
#pragma unroll
            for (int ks = 0; ks < 2; ks++) {
                a[bk][ks] = *(const f16x8*)(AsB + aoff[bk][ks]);
                b[bk][ks] = *(const f16x8*)(BsB + boff[bk][ks]);
            }
#pragma unroll
        for (int mb = 0; mb < 2; mb++)
#pragma unroll
            for (int nb = 0; nb < 2; nb++) {
                acc[mb][nb] = MFMA32_F16(b[nb][0], a[mb][0], acc[mb][nb]);
                acc[mb][nb] = MFMA32_F16(b[nb][1], a[mb][1], acc[mb][nb]);
            }
    }

    // region uniform per block: 0=Q, 1=K, 2=V
    const int region = n0 >> 10;
#pragma unroll
    for (int mb = 0; mb < 2; mb++) {
        int row = m0 + wm + mb * 32 + l32;       // token 0..16383
        int b_ = row >> 13, n_ = row & 8191;
        int win = n_ >> 9, i_ = n_ & 511;
        float fn = (float)n_;
#pragma unroll
        for (int nb = 0; nb < 2; nb++) {
            int colb = n0 + wn + nb * 32 + half * 4;
            int cr = colb & 1023;                 // feature idx within region
            int h = cr >> 6;
            int d0 = cr & 63;                     // multiple of 4
            int wh = ((b_ * 16 + win) << 4) + h;
            if (region < 2) {
                f16* base = (region == 0)
                    ? (Qb + ((size_t)wh * 512 + i_) * 64)
                    : (Kb + ((size_t)wh * 576 + 16 + i_) * 64);
#pragma unroll
                for (int q = 0; q < 4; q++) {
                    int d = d0 + q * 8;
                    float j0f = (float)(d >> 1);
                    float ang0 = fn * exp2f(-LOG2_10K_32 * j0f);
                    float ang1 = fn * exp2f(-LOG2_10K_32 * (j0f + 1.0f));
                    float s0, c0f, s1, c1f;
                    sincosf(ang0, &s0, &c0f);
                    sincosf(ang1, &s1, &c1f);
                    float x0 = (float)(f16)acc[mb][nb][q * 4 + 0];
                    float x1 = (float)(f16)acc[mb][nb][q * 4 + 1];
                    float x2 = (float)(f16)acc[mb][nb][q * 4 + 2];
                    float x3 = (float)(f16)acc[mb][nb][q * 4 + 3];
                    f16x4 ov;
                    ov[0] = (f16)(x0 * c0f - x1 * s0);
                    ov[1] = (f16)(x1 * c0f + x0 * s0);
                    ov[2] = (f16)(x2 * c1f - x3 * s1);
                    ov[3] = (f16)(x3 * c1f + x2 * s1);
                    *(f16x4*)(base + d) = ov;
                }
            } else {
                f16* vbase = Vt + (size_t)wh * 36864 + 16 + i_;
#pragma unroll
                for (int q = 0; q < 4; q++)
#pragma unroll
                    for (int r = 0; r < 4; r++)
                        vbase[(size_t)(d0 + q * 8 + r) * 576] = (f16)acc[mb][nb][q * 4 + r];
            }
        }
    }
}

// ---------------------------------------------------------------- out GEMM (256^2 ring-4 counted-vmcnt; confirmed ~25us)
__global__ __launch_bounds__(512, 2) void k_gemm_out(
        const f16* __restrict__ A, const f16* __restrict__ BT,
        float* __restrict__ C, int M, int N, int Kp) {
    const int K = 1024;
    const int NT = 32;
    __shared__ __align__(16) char ldsA[65536];
    __shared__ __align__(16) char ldsB[65536];
    const int t = threadIdx.x;
    const int lane = t & 63, wave = t >> 6, l32 = lane & 31, half = lane >> 5;
    const int m0 = blockIdx.y * 256, n0 = blockIdx.x * 256;
    const int wm = (wave >> 2) * 128, wn = (wave & 3) * 64;

    f32x16 acc[4][2];
#pragma unroll
    for (int i = 0; i < 4; i++)
#pragma unroll
        for (int j = 0; j < 2; j++)
#pragma unroll
            for (int r = 0; r < 16; r++) acc[i][j][r] = 0.f;

    uint32_t aoff[4][2], boff[2][2];
#pragma unroll
    for (int mb = 0; mb < 4; mb++)
#pragma unroll
        for (int ks = 0; ks < 2; ks++)
            aoff[mb][ks] = swz((uint32_t)(wm + mb * 32 + l32) * 4 + ks * 2 + half) * 16;
#pragma unroll
    for (int nb = 0; nb < 2; nb++)
#pragma unroll
        for (int ks = 0; ks < 2; ks++)
            boff[nb][ks] = swz((uint32_t)(wn + nb * 32 + l32) * 4 + ks * 2 + half) * 16;

    uint32_t g0 = swz((uint32_t)t), g1 = swz((uint32_t)t + 512);
    const f16* Ag0 = A + (size_t)(m0 + (g0 >> 2)) * K + (g0 & 3) * 8;
    const f16* Ag1 = A + (size_t)(m0 + (g1 >> 2)) * K + (g1 & 3) * 8;
    const f16* Bg0 = BT + (size_t)(n0 + (g0 >> 2)) * K + (g0 & 3) * 8;
    const f16* Bg1 = BT + (size_t)(n0 + (g1 >> 2)) * K + (g1 & 3) * 8;

#pragma unroll
    for (int p = 0; p < 3; ++p) {
        char* dA = ldsA + p * 16384;
        async_ld16(dA + t * 16, Ag0 + p * 32);
        async_ld16(dA + (t + 512) * 16, Ag1 + p * 32);
        char* dB = ldsB + p * 16384;
        async_ld16(dB + t * 16, Bg0 + p * 32);
        async_ld16(dB + (t + 512) * 16, Bg1 + p * 32);
    }
    __builtin_amdgcn_s_waitcnt(0x0f78);   // vmcnt(8)
    __builtin_amdgcn_s_barrier();
    __builtin_amdgcn_sched_barrier(0);

#pragma unroll 4
    for (int kt = 0; kt < NT; ++kt) {
        char* As_s = ldsA + (kt & 3) * 16384;
        char* Bs_s = ldsB + (kt & 3) * 16384;
        f16x8 a00 = *(const f16x8*)(As_s + aoff[0][0]);
        f16x8 a01 = *(const f16x8*)(As_s + aoff[0][1]);
        f16x8 a10 = *(const f16x8*)(As_s + aoff[1][0]);
        f16x8 a11 = *(const f16x8*)(As_s + aoff[1][1]);
        f16x8 b00 = *(const f16x8*)(Bs_s + boff[0][0]);
        f16x8 b01 = *(const f16x8*)(Bs_s + boff[0][1]);
        f16x8 b10 = *(const f16x8*)(Bs_s + boff[1][0]);
        f16x8 b11 = *(const f16x8*)(Bs_s + boff[1][1]);
        if (kt < NT - 3) {
            char* dA = ldsA + ((kt + 3) & 3) * 16384;
            async_ld16(dA + t * 16, Ag0 + (kt + 3) * 32);
            async_ld16(dA + (t + 512) * 16, Ag1 + (kt + 3) * 32);
        }
        __builtin_amdgcn_s_barrier();
        __builtin_amdgcn_s_setprio(1);
        acc[0][0] = MFMA32_F16(b00, a00, acc[0][0]);
        acc[0][0] = MFMA32_F16(b01, a01, acc[0][0]);
        acc[0][1] = MFMA32_F16(b10, a00, acc[0][1]);
        acc[0][1] = MFMA32_F16(b11, a01, acc[0][1]);
        acc[1][0] = MFMA32_F16(b00, a10, acc[1][0]);
        acc[1][0] = MFMA32_F16(b01, a11, acc[1][0]);
        acc[1][1] = MFMA32_F16(b10, a10, acc[1][1]);
        acc[1][1] = MFMA32_F16(b11, a11, acc[1][1]);
        __builtin_amdgcn_s_setprio(0);
        __builtin_amdgcn_s_barrier();
        f16x8 a20 = *(const f16x8*)(As_s + aoff[2][0]);
        f16x8 a21 = *(const f16x8*)(As_s + aoff[2][1]);
        f16x8 a30 = *(const f16x8*)(As_s + aoff[3][0]);
        f16x8 a31 = *(const f16x8*)(As_s + aoff[3][1]);
        if (kt < NT - 3) {
            char* dB = ldsB + ((kt + 3) & 3) * 16384;
            async_ld16(dB + t * 16, Bg0 + (kt + 3) * 32);
            async_ld16(dB + (t + 512) * 16, Bg1 + (kt + 3) * 32);
        }
        __builtin_amdgcn_s_barrier();
        __builtin_amdgcn_s_setprio(1);
        acc[2][0] = MFMA32_F16(b00, a20, acc[2][0]);
        acc[2][0] = MFMA32_F16(b01, a21, acc[2][0]);
        acc[2][1] = MFMA32_F16(b10, a20, acc[2][1]);
        acc[2][1] = MFMA32_F16(b11, a21, acc[2][1]);
        acc[3][0] = MFMA32_F16(b00, a30, acc[3][0]);
        acc[3][0] = MFMA32_F16(b01, a31, acc[3][0]);
        acc[3][1] = MFMA32_F16(b10, a30, acc[3][1]);
        acc[3][1] = MFMA32_F16(b11, a31, acc[3][1]);
        __builtin_amdgcn_s_setprio(0);
        if (kt < NT - 3)       __builtin_amdgcn_s_waitcnt(0x0f78);
        else if (kt == NT - 3) __builtin_amdgcn_s_waitcnt(0x0f74);
        else if (kt == NT - 2) __builtin_amdgcn_s_waitcnt(0x0f70);
        __builtin_amdgcn_s_barrier();
        __builtin_amdgcn_sched_barrier(0);
    }

#pragma unroll
    for (int mb = 0; mb < 4; mb++) {
        int row = m0 + wm + mb * 32 + l32;
#pragma unroll
        for (int nb = 0; nb < 2; nb++) {
            int colb = n0 + wn + nb * 32 + half * 4;
#pragma unroll
            for (int q = 0; q < 4; q++) {
                f32x4 ov;
#pragma unroll
                for (int r = 0; r < 4; r++) ov[r] = acc[mb][nb][q * 4 + r];
                *(f32x4*)(C + (size_t)row * N + colb + q * 8) = ov;
            }
        }
    }
    (void)M; (void)Kp;
}

// ---------------------------------------------------------------- attention
// R15 = R11 + wave-uniform fully-masked-tile skip. Staging is block-wide but
// causality is per-wave: wave w only has unmasked columns for j0 <= i0+16w+31.
// ~1/3 of wave-tile computes are on fully-masked tiles whose contribution is
// exactly zero (p=exp(-1e30-m)=0, rsum=0, mx=-1e30<=m_l -> skip-rescale path
// leaves o,m_l,l_l untouched) -> skipping the compute is bit-identical.
// Barriers + staging stay unconditional (every wave executes every barrier).
__global__ __launch_bounds__(512) void k_attn(
        const f16* __restrict__ Q, const f16* __restrict__ Kb,
        const f16* __restrict__ Vt, f16* __restrict__ AO) {
    const int bid = blockIdx.x;
    const int wh = ((bid >> 5) << 3) | (bid & 7);   // bid = 32*(wh>>3) + 8*pair + (wh&7)
    const int pair = (bid >> 3) & 3;
    const int i0 = pair * 128;
    const int t = threadIdx.x, lane = t & 63, wave = t >> 6, quad = lane >> 4, l16 = lane & 15;
    __shared__ f16 Ks[64 * 64];
    __shared__ f16 Vs[64 * 64];
    __shared__ f16 Ps[8][16][80];

    const int ig = i0 + wave * 16 + l16;
    const f16* qptr = Q + ((size_t)wh * 512 + ig) * 64 + quad * 8;
    f16x8 qf0 = *(const f16x8*)(qptr);
    f16x8 qf1 = *(const f16x8*)(qptr + 32);

    const f32x4 zero = {0.f, 0.f, 0.f, 0.f};
    f32x4 o[4];
#pragma unroll
    for (int i = 0; i < 4; i++) o[i] = zero;
    float m_l = -1e30f, l_l = 0.f;

    uint32_t g = swz((uint32_t)t);                   // 512 granules, 1 load/thread
    const f16* kg0 = Kb + ((size_t)wh * 576 + (g >> 3)) * 64 + (g & 7) * 8;
    const f16* vg0 = Vt + ((size_t)wh * 64 + (g >> 3)) * 576 + (g & 7) * 8;
    char* KsB = (char*)Ks;
    char* VsB = (char*)Vs;

    uint32_t boff[4][2];
#pragma unroll
    for (int i = 0; i < 4; i++)
#pragma unroll
        for (int f = 0; f < 2; f++)
            boff[i][f] = swz((uint32_t)(i * 16 + l16) * 8 + f * 4 + quad) * 16;

    f16* psrow = &Ps[wave][l16][0];
    int njt = 2 * pair + 3;
    if (njt > 9) njt = 9;

    const int jcap = (ig + 16 < 527) ? (ig + 16) : 527;   // jg<=ig+16 && jg<528
    const int wlim = i0 + wave * 16 + 31;                 // tile active iff j0 <= wlim

    // prologue: load tile 0 into regs (pre-swizzled global addr, linear LDS dest)
    f16x8 kreg = *(const f16x8*)(kg0);
    f16x8 vreg = *(const f16x8*)(vg0);

    for (int jt = 0; jt < njt; jt++) {
        const int j0 = jt * 64;
        // B1: all waves done reading LDS of tile jt-1 (raw barrier: no vmcnt drain)
        __builtin_amdgcn_sched_barrier(0);
        __builtin_amdgcn_s_barrier();
        __builtin_amdgcn_sched_barrier(0);
        *(f16x8*)(KsB + t * 16) = kreg;
        *(f16x8*)(VsB + t * 16) = vreg;
        if (jt + 1 < njt) {
            kreg = *(const f16x8*)(kg0 + (size_t)(j0 + 64) * 64);
            vreg = *(const f16x8*)(vg0 + (j0 + 64));
        }
        // B2: this tile's LDS writes visible to all waves
        __builtin_amdgcn_s_waitcnt(0xc07f);  // lgkmcnt(0): own ds_writes done
        __builtin_amdgcn_sched_barrier(0);
        __builtin_amdgcn_s_barrier();
        __builtin_amdgcn_sched_barrier(0);

        // wave-uniform skip: tile fully masked for every lane of this wave ->
        // contribution is exactly zero; o, m_l, l_l unchanged (bit-identical)
        if (j0 > wlim) continue;

        f32x4 s[4];
#pragma unroll
        for (int jb = 0; jb < 4; jb++) {
            f16x8 kv0 = *(const f16x8*)(KsB + boff[jb][0]);
            f16x8 kv1 = *(const f16x8*)(KsB + boff[jb][1]);
            f32x4 z = zero;
            z = MFMA_F16(kv0, qf0, z);
            z = MFMA_F16(kv1, qf1, z);
            s[jb] = z;
        }

        // wave-uniform: tile fully unmasked for every lane of this wave?
        const bool fullt = (j0 + 63 <= i0 + wave * 16 + 16) && (j0 + 64 <= 528);
        float mx = -1e30f;
        if (fullt) {
#pragma unroll
            for (int jb = 0; jb < 4; jb++)
#pragma unroll
                for (int r = 0; r < 4; r++) {
                    float val = s[jb][r] * 0.125f;
                    s[jb][r] = val;
                    mx = fmaxf(mx, val);
                }
        } else {
#pragma unroll
            for (int jb = 0; jb < 4; jb++)
#pragma unroll
                for (int r = 0; r < 4; r++) {
                    int jg = j0 + jb * 16 + quad * 4 + r;
                    float val = (jg <= jcap) ? s[jb][r] * 0.125f : -1e30f;
                    s[jb][r] = val;
                    mx = fmaxf(mx, val);
                }
        }
        mx = fmaxf(mx, __shfl_xor(mx, 16, 64));
        mx = fmaxf(mx, __shfl_xor(mx, 32, 64));
        const bool skipresc = __all(mx <= m_l);        // -> mnew==m_l, alpha==1 exactly
        float mnew = fmaxf(m_l, mx);
        float alpha = 1.0f;
        if (!skipresc) alpha = __expf(m_l - mnew);
        m_l = mnew;
        float rsum = 0.f;
#pragma unroll
        for (int jb = 0; jb < 4; jb++) {
            f16x4 pw;
#pragma unroll
            for (int r = 0; r < 4; r++) {
                float p = __expf(s[jb][r] - mnew);
                rsum += p;
                pw[r] = (f16)p;
            }
            *(f16x4*)(psrow + jb * 16 + quad * 4) = pw;
        }
        rsum += __shfl_xor(rsum, 16, 64);
        rsum += __shfl_xor(rsum, 32, 64);
        if (skipresc) {
            l_l = l_l + rsum;                          // == l_l*1.0f + rsum bitwise
        } else {
            l_l = l_l * alpha + rsum;
#pragma unroll
            for (int nd = 0; nd < 4; nd++) o[nd] *= alpha;
        }

        // Ps is wave-local: wave-level DS completion suffices (no barrier)
        __builtin_amdgcn_s_waitcnt(0xc07f);  // lgkmcnt(0)
        __builtin_amdgcn_sched_barrier(0);

        f16x8 pb0 = *(const f16x8*)(psrow + quad * 8);
        f16x8 pb1 = *(const f16x8*)(psrow + 32 + quad * 8);
#pragma unroll
        for (int nd = 0; nd < 4; nd++) {
            f16x8 v0 = *(const f16x8*)(VsB + boff[nd][0]);
            f16x8 v1 = *(const f16x8*)(VsB + boff[nd][1]);
            o[nd] = MFMA_F16(v0, pb0, o[nd]);
            o[nd] = MFMA_F16(v1, pb1, o[nd]);
        }
    }

    const int bw = wh >> 4, h = wh & 15;
    float inv = 1.f / l_l;
    f16* dst = AO + ((size_t)bw * 512 + ig) * 1024 + h * 64 + quad * 4;
#pragma unroll
    for (int nd = 0; nd < 4; nd++) {
        f16x4 ov;
#pragma unroll
        for (int r = 0; r < 4; r++) ov[r] = (f16)(o[nd][r] * inv);
        *(f16x4*)(dst + nd * 16) = ov;
    }
}

// ---------------------------------------------------------------- launch
extern "C" void kernel_launch(void* const* d_in, const int* in_sizes, int n_in,
                              void* d_out, int out_size, void* d_ws, size_t ws_size,
                              hipStream_t stream) {
    const float* seq   = (const float*)d_in[0];
    const float* wnorm = (const float*)d_in[1];
    const float* Wqkv  = (const float*)d_in[2];
    const float* Wout  = (const float*)d_in[3];
    const float* pm    = (const float*)d_in[4];
    float* out = (float*)d_out;
    char* ws = (char*)d_ws;

    f16* WqkvT = (f16*)(ws + 0);            // 3072x1024  = 6 MB
    f16* WoutT = (f16*)(ws + 6291456);      // 1024x1024  = 2 MB
    f16* X     = (f16*)(ws + 8388608);      // 16384x1024 = 32 MB
    f16* Qb    = (f16*)(ws + 41943040);     // 512x512x64 = 32 MB
    f16* AO    = (f16*)(ws + 75497472);     // 16384x1024 = 32 MB
    f16* Kb    = (f16*)(ws + 109051904);    // 512x576x64 = 36 MB
    f16* Vt    = (f16*)(ws + 146800640);    // 512x64x576 = 36 MB  (end 176 MB)

    k_prep<<<20992, 256, 0, stream>>>(Wqkv, Wout, WqkvT, WoutT, seq, wnorm, X, pm, Kb, Vt);
    k_gemm_qkv<<<dim3(24, 128), 256, 0, stream>>>(X, WqkvT, Qb, Kb, Vt);
    k_attn<<<2048, 512, 0, stream>>>(Qb, Kb, Vt, AO);
    k_gemm_out<<<dim3(4, 64), 512, 0, stream>>>(AO, WoutT, out, 16384, 1024, 1024);
}